// Round 6
// baseline (303.355 us; speedup 1.0000x reference)
//
#include <hip/hip_runtime.h>

#define BB 8
#define NN 128
#define CC 64
#define LL 3
#define HH 128
#define NEG 0.01f
#define NPOS (BB*NN*NN)   // 131072

typedef __attribute__((ext_vector_type(8))) short shortx8;   // 8 bf16 = 4 VGPRs
typedef __attribute__((ext_vector_type(4))) float f32x4;

// ---- workspace layout (float offsets) ----
#define OFF_HHI   0L          // h hi: 131072*64 shorts = 4194304 floats
#define OFF_HLO   4194304L    // h lo
#define OFF_XN    8388608L    // inter-layer x (bf16): 4194304 floats
#define OFF_RS    12582912L   // rowsum fp32 [1024][64]
#define OFF_DG    12648448L   // diag fp32 [1024][64]
#define OFF_RCDH  12713984L   // RCD hi [1024][192] shorts = 98304 floats
#define OFF_RCDL  12812288L
#define OFF_U     12911616L   // [1024][64]
#define OFF_V     12977152L
#define OFF_D     13042688L
#define OFF_SB    13108224L   // bf16 const region (shorts)
// sb short offsets: wb1@0 (L*128*64), wb2@24576 (L*128*128), wb3@73728 (L*64*128),
//   c9h@98304, c9l@110592, c10h@122880, c10l@135168 (each L*64*64, [l][s][d]),
//   Kh@147456, Kl@258048 (each L*192*192, [l][out][k])

__device__ __forceinline__ float leaky(float v) { return v >= 0.f ? v : NEG * v; }

__device__ __forceinline__ short f2bf(float f) {   // RNE float -> bf16
    unsigned u = __builtin_bit_cast(unsigned, f);
    u += 0x7fff + ((u >> 16) & 1);
    return (short)(u >> 16);
}
__device__ __forceinline__ float bf2f(short s) {
    unsigned u = ((unsigned)(unsigned short)s) << 16;
    return __builtin_bit_cast(float, u);
}
__device__ __forceinline__ unsigned pkf(float a, float b) {  // two f32 -> packed bf16x2
    return (unsigned)(unsigned short)f2bf(a) | ((unsigned)(unsigned short)f2bf(b) << 16);
}
__device__ __forceinline__ unsigned pks(short a, short b) {
    return (unsigned)(unsigned short)a | ((unsigned)(unsigned short)b << 16);
}
__device__ __forceinline__ shortx8 cvt8(const float* p) {    // 8 f32 -> 8 bf16
    float4 f0 = *(const float4*)p, f1 = *(const float4*)(p + 4);
    shortx8 r;
    r[0]=f2bf(f0.x); r[1]=f2bf(f0.y); r[2]=f2bf(f0.z); r[3]=f2bf(f0.w);
    r[4]=f2bf(f1.x); r[5]=f2bf(f1.y); r[6]=f2bf(f1.z); r[7]=f2bf(f1.w);
    return r;
}

// ---------------- prep: bf16 weights, split c9/c10 [s][d], split K-matrix [out][k] ----------------
__global__ void prep_kernel(const float* __restrict__ w1, const float* __restrict__ w2,
                            const float* __restrict__ w3, const float* __restrict__ coefs,
                            float* __restrict__ ws) {
    long idx = (long)blockIdx.x * 256 + threadIdx.x;
    short* sb = (short*)(ws + OFF_SB);
    if (idx < 24576) {                       // wb1[l][h][c]
        sb[idx] = f2bf(w1[idx]);
    } else if (idx < 73728) {                // wb2[l][h][k]
        sb[idx] = f2bf(w2[idx - 24576]);
    } else if (idx < 98304) {                // wb3[l][c][k]
        sb[idx] = f2bf(w3[idx - 73728]);
    } else if (idx < 110592) {               // c9 hi/lo [l][s][d]
        long r = idx - 98304; int l = (int)(r / 4096); int q = (int)(r % 4096);
        int s = q >> 6, d = q & 63;
        float v = coefs[(((long)l*CC + d)*CC + s)*15 + 9];
        short hi = f2bf(v);
        sb[98304 + r]  = hi;
        sb[110592 + r] = f2bf(v - bf2f(hi));
    } else if (idx < 122880) {               // c10 hi/lo [l][s][d]
        long r = idx - 110592; int l = (int)(r / 4096); int q = (int)(r % 4096);
        int s = q >> 6, d = q & 63;
        float v = coefs[(((long)l*CC + d)*CC + s)*15 + 10];
        short hi = f2bf(v);
        sb[122880 + r] = hi;
        sb[135168 + r] = f2bf(v - bf2f(hi));
    } else if (idx < 233472) {               // Kbig hi/lo [l][out 192][k 192]
        long r = idx - 122880;
        int l = (int)(r / 36864); int q = (int)(r % 36864);
        int o = q / 192, k = q % 192;
        int wo = o >> 6, s = o & 63, wk = k >> 6, d = k & 63;
        const int sel[3][3] = {{5,6,11},{7,8,12},{3,2,0}};
        float v = coefs[(((long)l*CC + d)*CC + s)*15 + sel[wo][wk]];
        short hi = f2bf(v);
        sb[147456 + r] = hi;
        sb[258048 + r] = f2bf(v - bf2f(hi));
    }
}

// ---------------- MFMA fused 3-stage MLP ----------------
// Swapped operands (W = A-frag, x = B-frag). Stage-1 B-frags read DIRECT from global
// (no x LDS tile, no sync). Stage-2 weight frags prefetched at kernel top; stage-3
// frags issued before sync #1 so their latency hides under stage-2 MFMA.
// LDS: h1@0 (64x128 bf16, 256B rows, swz), h2@16384. 32KB total.
__global__ __launch_bounds__(256, 4) void mlp_kernel(
    const float* __restrict__ xf, const short* __restrict__ xb,
    const float* __restrict__ mask,
    const float* __restrict__ b1, const float* __restrict__ b2, const float* __restrict__ b3,
    const short* __restrict__ wb1, const short* __restrict__ wb2, const short* __restrict__ wb3,
    short* __restrict__ hhi, short* __restrict__ hlo)
{
    __shared__ __align__(16) char lds[32768];
    const int t = threadIdx.x;
    const int lane = t & 63;
    const int w = t >> 6;
    const int arow = lane & 15;
    const int kgrp = lane >> 4;
    const long pos0 = (long)blockIdx.x * 64;

    // ---- prefetch stage-2 weight fragments (32 VGPR) ----
    shortx8 W2[4][2];
    #pragma unroll
    for (int kk = 0; kk < 4; ++kk)
        #pragma unroll
        for (int of = 0; of < 2; ++of)
            W2[kk][of] = *(const shortx8*)(wb2 + (long)(w*32 + of*16 + arow)*HH + kk*32 + kgrp*8);

    // ---- stage 1: B-frags direct from global ----
    {
        f32x4 acc[2][4];
        #pragma unroll
        for (int of = 0; of < 2; ++of)
            #pragma unroll
            for (int pf = 0; pf < 4; ++pf) acc[of][pf] = (f32x4){0.f,0.f,0.f,0.f};
        #pragma unroll
        for (int kk = 0; kk < 2; ++kk) {
            shortx8 bx[4];
            #pragma unroll
            for (int pf = 0; pf < 4; ++pf) {
                const long off = (pos0 + pf*16 + arow)*CC + kk*32 + kgrp*8;
                bx[pf] = xb ? *(const shortx8*)(xb + off) : cvt8(xf + off);
            }
            #pragma unroll
            for (int of = 0; of < 2; ++of) {
                const shortx8 a = *(const shortx8*)(wb1 + (long)(w*32 + of*16 + arow)*CC + kk*32 + kgrp*8);
                #pragma unroll
                for (int pf = 0; pf < 4; ++pf)
                    acc[of][pf] = __builtin_amdgcn_mfma_f32_16x16x32_bf16(a, bx[pf], acc[of][pf], 0, 0, 0);
            }
        }
        #pragma unroll
        for (int of = 0; of < 2; ++of) {
            const int o0 = w*32 + of*16 + kgrp*4;
            const float4 bv = *(const float4*)(b1 + o0);
            #pragma unroll
            for (int pf = 0; pf < 4; ++pf) {
                const int p = pf*16 + arow;
                unsigned u0 = pkf(leaky(acc[of][pf][0] + bv.x), leaky(acc[of][pf][1] + bv.y));
                unsigned u1 = pkf(leaky(acc[of][pf][2] + bv.z), leaky(acc[of][pf][3] + bv.w));
                *(uint2*)(&lds[p*256 + ((o0*2) ^ ((p & 7) << 4))]) = make_uint2(u0, u1);
            }
        }
    }

    // ---- prefetch stage-3 weight frags + bias; latency hides under stage-2 ----
    shortx8 W3[4];
    #pragma unroll
    for (int kk = 0; kk < 4; ++kk)
        W3[kk] = *(const shortx8*)(wb3 + (long)(w*16 + arow)*HH + kk*32 + kgrp*8);
    const float4 B3 = *(const float4*)(b3 + w*16 + kgrp*4);
    __syncthreads();

    // ---- stage 2 ----
    {
        f32x4 acc[2][4];
        #pragma unroll
        for (int of = 0; of < 2; ++of)
            #pragma unroll
            for (int pf = 0; pf < 4; ++pf) acc[of][pf] = (f32x4){0.f,0.f,0.f,0.f};
        #pragma unroll
        for (int kk = 0; kk < 4; ++kk) {
            shortx8 bx[4];
            #pragma unroll
            for (int pf = 0; pf < 4; ++pf) {
                const int p = pf*16 + arow;
                bx[pf] = *(const shortx8*)(&lds[p*256 + ((kk*64 + kgrp*16) ^ ((p & 7) << 4))]);
            }
            #pragma unroll
            for (int of = 0; of < 2; ++of)
                #pragma unroll
                for (int pf = 0; pf < 4; ++pf)
                    acc[of][pf] = __builtin_amdgcn_mfma_f32_16x16x32_bf16(W2[kk][of], bx[pf], acc[of][pf], 0, 0, 0);
        }
        #pragma unroll
        for (int of = 0; of < 2; ++of) {
            const int o0 = w*32 + of*16 + kgrp*4;
            const float4 bv = *(const float4*)(b2 + o0);
            #pragma unroll
            for (int pf = 0; pf < 4; ++pf) {
                const int p = pf*16 + arow;
                unsigned u0 = pkf(leaky(acc[of][pf][0] + bv.x), leaky(acc[of][pf][1] + bv.y));
                unsigned u1 = pkf(leaky(acc[of][pf][2] + bv.z), leaky(acc[of][pf][3] + bv.w));
                *(uint2*)(&lds[16384 + p*256 + ((o0*2) ^ ((p & 7) << 4))]) = make_uint2(u0, u1);
            }
        }
    }
    __syncthreads();

    // ---- stage 3: direct split-bf16 global store ----
    {
        f32x4 acc[4];
        #pragma unroll
        for (int pf = 0; pf < 4; ++pf) acc[pf] = (f32x4){0.f,0.f,0.f,0.f};
        #pragma unroll
        for (int kk = 0; kk < 4; ++kk) {
            #pragma unroll
            for (int pf = 0; pf < 4; ++pf) {
                const int p = pf*16 + arow;
                const shortx8 bx = *(const shortx8*)(&lds[16384 + p*256 + ((kk*64 + kgrp*16) ^ ((p & 7) << 4))]);
                acc[pf] = __builtin_amdgcn_mfma_f32_16x16x32_bf16(W3[kk], bx, acc[pf], 0, 0, 0);
            }
        }
        const int o0 = w*16 + kgrp*4;
        #pragma unroll
        for (int pf = 0; pf < 4; ++pf) {
            const int p = pf*16 + arow;
            const long pos = pos0 + p;
            const float mv = mask[pos];
            short hi[4], lo[4];
            float vals[4] = {acc[pf][0] + B3.x, acc[pf][1] + B3.y, acc[pf][2] + B3.z, acc[pf][3] + B3.w};
            #pragma unroll
            for (int r = 0; r < 4; ++r) {
                float v = leaky(vals[r]) * mv;
                hi[r] = f2bf(v);
                lo[r] = f2bf(v - bf2f(hi[r]));
            }
            *(uint2*)(hhi + pos*CC + o0) = make_uint2(pks(hi[0], hi[1]), pks(hi[2], hi[3]));
            *(uint2*)(hlo + pos*CC + o0) = make_uint2(pks(lo[0], lo[1]), pks(lo[2], lo[3]));
        }
    }
}

// ---------------- vectorized reductions: 16B loads, colsum/rowsum/diag ----------------
__global__ __launch_bounds__(256) void reduce_kernel(const short* __restrict__ hhi,
                                                     const short* __restrict__ hlo,
                                                     float* __restrict__ rowsum,
                                                     float* __restrict__ diag,
                                                     short* __restrict__ rcdh,
                                                     short* __restrict__ rcdl) {
    const int br = blockIdx.x;            // n*128 + r
    const int n = br >> 7, r = br & 127;
    const int t = threadIdx.x;
    const int c8 = (t & 7) * 8;           // 8-channel slice
    const int g = t >> 3;                 // 32 groups
    __shared__ float red[32][64];
    const long rowbase = ((long)(n*NN + r) * NN) * CC;

    // row pass: sum over j
    {
        float s[8];
        #pragma unroll
        for (int e = 0; e < 8; ++e) s[e] = 0.f;
        for (int j = g; j < NN; j += 32) {
            const long idx = rowbase + (long)j*CC + c8;
            const shortx8 vh = *(const shortx8*)(hhi + idx);
            const shortx8 vl = *(const shortx8*)(hlo + idx);
            #pragma unroll
            for (int e = 0; e < 8; ++e) s[e] += bf2f(vh[e]) + bf2f(vl[e]);
        }
        #pragma unroll
        for (int e = 0; e < 8; ++e) red[g][c8 + e] = s[e];
    }
    __syncthreads();
    if (t < 64) {
        float rs = 0.f;
        #pragma unroll
        for (int k = 0; k < 32; ++k) rs += red[k][t];
        rowsum[(long)br*CC + t] = rs;
        short h = f2bf(rs);
        rcdh[(long)br*192 + 64 + t] = h;
        rcdl[(long)br*192 + 64 + t] = f2bf(rs - bf2f(h));
    }
    __syncthreads();

    // col pass: sum over i
    {
        const long colbase = ((long)n*NN*NN + r) * CC;
        float s[8];
        #pragma unroll
        for (int e = 0; e < 8; ++e) s[e] = 0.f;
        for (int i = g; i < NN; i += 32) {
            const long idx = colbase + (long)i*NN*CC + c8;
            const shortx8 vh = *(const shortx8*)(hhi + idx);
            const shortx8 vl = *(const shortx8*)(hlo + idx);
            #pragma unroll
            for (int e = 0; e < 8; ++e) s[e] += bf2f(vh[e]) + bf2f(vl[e]);
        }
        #pragma unroll
        for (int e = 0; e < 8; ++e) red[g][c8 + e] = s[e];
    }
    __syncthreads();
    if (t < 64) {
        float cs = 0.f;
        #pragma unroll
        for (int k = 0; k < 32; ++k) cs += red[k][t];
        short h = f2bf(cs);
        rcdh[(long)br*192 + t] = h;
        rcdl[(long)br*192 + t] = f2bf(cs - bf2f(h));
        const long didx = rowbase + (long)r*CC + t;
        float dg = bf2f(hhi[didx]) + bf2f(hlo[didx]);
        diag[(long)br*CC + t] = dg;
        short hd = f2bf(dg);
        rcdh[(long)br*192 + 128 + t] = hd;
        rcdl[(long)br*192 + 128 + t] = f2bf(dg - bf2f(hd));
    }
}

// ---------------- U/V/D via MFMA, with trace/total biases computed in-block ----------------
__global__ __launch_bounds__(256) void uvd_kernel(
    const short* __restrict__ rcdh, const short* __restrict__ rcdl,
    const short* __restrict__ kh, const short* __restrict__ kl,
    const float* __restrict__ rowsum, const float* __restrict__ diag,
    const float* __restrict__ coefs, int layer,
    float* __restrict__ U, float* __restrict__ V, float* __restrict__ D)
{
    __shared__ float ra[4][64], rb[4][64];
    __shared__ float ub[64], db[64];
    const int t = threadIdx.x, lane = t & 63, w = t >> 6;
    const int arow = lane & 15, kgrp = lane >> 4;
    const int r0 = blockIdx.x * 64;
    const int nb = r0 >> 7;

    // ---- in-block trace/total -> ub/db (redundant across the 2 blocks of each n) ----
    {
        const int c = t & 63, g = t >> 6;
        float a = 0.f, b = 0.f;
        for (int i = g; i < NN; i += 4) {
            a += rowsum[((long)nb*NN + i)*CC + c];
            b += diag[((long)nb*NN + i)*CC + c];
        }
        ra[g][c] = a; rb[g][c] = b;
    }
    __syncthreads();
    if (t < 128) {
        const int which = t >> 6, s = t & 63;
        const float* cf = coefs + (long)layer*CC*CC*15;
        float acc = 0.f;
        for (int d = 0; d < CC; ++d) {
            const float tt = ra[0][d] + ra[1][d] + ra[2][d] + ra[3][d];
            const float tr = rb[0][d] + rb[1][d] + rb[2][d] + rb[3][d];
            const float* cds = cf + ((long)d*CC + s)*15;
            if (which == 0) acc += cds[13]*tr + cds[14]*tt;
            else            acc += cds[1]*tr + cds[4]*tt;
        }
        if (which == 0) ub[s] = acc; else db[s] = acc;
    }
    __syncthreads();

    f32x4 acc[3][4];
    #pragma unroll
    for (int o = 0; o < 3; ++o)
        #pragma unroll
        for (int pf = 0; pf < 4; ++pf) acc[o][pf] = (f32x4){0.f,0.f,0.f,0.f};
    #pragma unroll
    for (int kk = 0; kk < 6; ++kk) {
        shortx8 bh[4], bl[4];
        #pragma unroll
        for (int pf = 0; pf < 4; ++pf) {
            const long off = (long)(r0 + pf*16 + arow)*192 + kk*32 + kgrp*8;
            bh[pf] = *(const shortx8*)(rcdh + off);
            bl[pf] = *(const shortx8*)(rcdl + off);
        }
        #pragma unroll
        for (int o = 0; o < 3; ++o) {
            const long aoff = (long)((w*3 + o)*16 + arow)*192 + kk*32 + kgrp*8;
            const shortx8 ah = *(const shortx8*)(kh + aoff);
            const shortx8 al = *(const shortx8*)(kl + aoff);
            #pragma unroll
            for (int pf = 0; pf < 4; ++pf) {
                acc[o][pf] = __builtin_amdgcn_mfma_f32_16x16x32_bf16(ah, bh[pf], acc[o][pf], 0, 0, 0);
                acc[o][pf] = __builtin_amdgcn_mfma_f32_16x16x32_bf16(ah, bl[pf], acc[o][pf], 0, 0, 0);
                acc[o][pf] = __builtin_amdgcn_mfma_f32_16x16x32_bf16(al, bh[pf], acc[o][pf], 0, 0, 0);
            }
        }
    }
    #pragma unroll
    for (int o = 0; o < 3; ++o) {
        const int o16 = (w*3 + o)*16;
        const int o0 = o16 + kgrp*4;
        #pragma unroll
        for (int pf = 0; pf < 4; ++pf) {
            const long rr = r0 + pf*16 + arow;
            float4 a = make_float4(acc[o][pf][0], acc[o][pf][1], acc[o][pf][2], acc[o][pf][3]);
            if (o16 < 64) {
                a.x += ub[o0]; a.y += ub[o0+1]; a.z += ub[o0+2]; a.w += ub[o0+3];
                *(float4*)(U + rr*CC + o0) = a;
            } else if (o16 < 128) {
                *(float4*)(V + rr*CC + (o0 - 64)) = a;
            } else {
                const int q = o0 - 128;
                a.x += db[q]; a.y += db[q+1]; a.z += db[q+2]; a.w += db[q+3];
                *(float4*)(D + rr*CC + q) = a;
            }
        }
    }
}

// ---------------- Eq2to2: symmetric pair-block, c-frags prefetched, LDS-staged h ----------------
__global__ __launch_bounds__(256, 4) void eq_kernel(
    const short* __restrict__ hhi, const short* __restrict__ hlo,
    const float* __restrict__ mask,
    const short* __restrict__ c9h, const short* __restrict__ c9l,
    const short* __restrict__ c10h, const short* __restrict__ c10l,
    const float* __restrict__ U, const float* __restrict__ V, const float* __restrict__ D,
    const float* __restrict__ bias, const float* __restrict__ idbias,
    float* __restrict__ outf, short* __restrict__ outb)
{
    __shared__ __align__(16) char lds[32768];
    const int t = threadIdx.x, lane = t & 63, w = t >> 6;
    const int arow = lane & 15, kgrp = lane >> 4;
    const int n = blockIdx.y;
    const int pr = blockIdx.x;
    int it = (int)((sqrtf(8.f*pr + 1.f) - 1.f)*0.5f);
    while ((it+1)*(it+2)/2 <= pr) ++it;
    while (it*(it+1)/2 > pr) --it;
    const int jt = pr - it*(it+1)/2;      // jt <= it
    const int i0 = it*8, j0 = jt*8;
    const int s0 = w*16;

    // ---- prefetch c9/c10 fragments (32 VGPR) ----
    shortx8 A9h[2], A9l[2], A10h[2], A10l[2];
    #pragma unroll
    for (int kk = 0; kk < 2; ++kk) {
        const long co = (long)(s0 + arow)*CC + kk*32 + kgrp*8;
        A9h[kk]  = *(const shortx8*)(c9h  + co);
        A9l[kk]  = *(const shortx8*)(c9l  + co);
        A10h[kk] = *(const shortx8*)(c10h + co);
        A10l[kk] = *(const shortx8*)(c10l + co);
    }

    // ---- stage both tiles (hi/lo), coalesced 32B loads, swizzled 16B ds_writes ----
    {
        const int row = t >> 2, q = t & 3;
        const long posA = ((long)n*NN + i0 + (row >> 3))*NN + (j0 + (row & 7));
        const long posM = ((long)n*NN + j0 + (row & 7))*NN + (i0 + (row >> 3));
        const short* sAh = hhi + posA*CC + q*16;
        const short* sAl = hlo + posA*CC + q*16;
        const short* sMh = hhi + posM*CC + q*16;
        const short* sMl = hlo + posM*CC + q*16;
        shortx8 v0 = *(const shortx8*)(sAh);
        shortx8 v1 = *(const shortx8*)(sAh + 8);
        shortx8 v2 = *(const shortx8*)(sAl);
        shortx8 v3 = *(const shortx8*)(sAl + 8);
        shortx8 v4 = *(const shortx8*)(sMh);
        shortx8 v5 = *(const shortx8*)(sMh + 8);
        shortx8 v6 = *(const shortx8*)(sMl);
        shortx8 v7 = *(const shortx8*)(sMl + 8);
        const int swz = (row & 7) << 4;
        const int d0 = row*128 + ((q*32) ^ swz);
        const int d1 = row*128 + ((q*32 + 16) ^ swz);
        *(shortx8*)(&lds[d0]) = v0;          *(shortx8*)(&lds[d1]) = v1;
        *(shortx8*)(&lds[8192 + d0]) = v2;   *(shortx8*)(&lds[8192 + d1]) = v3;
        *(shortx8*)(&lds[16384 + d0]) = v4;  *(shortx8*)(&lds[16384 + d1]) = v5;
        *(shortx8*)(&lds[24576 + d0]) = v6;  *(shortx8*)(&lds[24576 + d1]) = v7;
    }
    __syncthreads();

    f32x4 accA[4], accM[4];
    #pragma unroll
    for (int pf = 0; pf < 4; ++pf) { accA[pf] = (f32x4){0.f,0.f,0.f,0.f}; accM[pf] = (f32x4){0.f,0.f,0.f,0.f}; }

    #pragma unroll
    for (int kk = 0; kk < 2; ++kk) {
        #pragma unroll
        for (int pf = 0; pf < 4; ++pf) {
            const int p = pf*16 + arow;
            const int off = (kk*64 + kgrp*16) ^ ((p & 7) << 4);
            const shortx8 Ah = *(const shortx8*)(&lds[p*128 + off]);
            const shortx8 Al = *(const shortx8*)(&lds[8192 + p*128 + off]);
            const shortx8 Mh = *(const shortx8*)(&lds[16384 + p*128 + off]);
            const shortx8 Ml = *(const shortx8*)(&lds[24576 + p*128 + off]);
            accA[pf] = __builtin_amdgcn_mfma_f32_16x16x32_bf16(A9h[kk],  Ah, accA[pf], 0, 0, 0);
            accA[pf] = __builtin_amdgcn_mfma_f32_16x16x32_bf16(A9h[kk],  Al, accA[pf], 0, 0, 0);
            accA[pf] = __builtin_amdgcn_mfma_f32_16x16x32_bf16(A9l[kk],  Ah, accA[pf], 0, 0, 0);
            accA[pf] = __builtin_amdgcn_mfma_f32_16x16x32_bf16(A10h[kk], Mh, accA[pf], 0, 0, 0);
            accA[pf] = __builtin_amdgcn_mfma_f32_16x16x32_bf16(A10h[kk], Ml, accA[pf], 0, 0, 0);
            accA[pf] = __builtin_amdgcn_mfma_f32_16x16x32_bf16(A10l[kk], Mh, accA[pf], 0, 0, 0);
            accM[pf] = __builtin_amdgcn_mfma_f32_16x16x32_bf16(A9h[kk],  Mh, accM[pf], 0, 0, 0);
            accM[pf] = __builtin_amdgcn_mfma_f32_16x16x32_bf16(A9h[kk],  Ml, accM[pf], 0, 0, 0);
            accM[pf] = __builtin_amdgcn_mfma_f32_16x16x32_bf16(A9l[kk],  Mh, accM[pf], 0, 0, 0);
            accM[pf] = __builtin_amdgcn_mfma_f32_16x16x32_bf16(A10h[kk], Ah, accM[pf], 0, 0, 0);
            accM[pf] = __builtin_amdgcn_mfma_f32_16x16x32_bf16(A10h[kk], Al, accM[pf], 0, 0, 0);
            accM[pf] = __builtin_amdgcn_mfma_f32_16x16x32_bf16(A10l[kk], Ah, accM[pf], 0, 0, 0);
        }
    }

    const int sc = s0 + kgrp*4;
    const float4 bv = *(const float4*)(bias + sc);
    #pragma unroll
    for (int pf = 0; pf < 4; ++pf) {
        const int p = pf*16 + arow;
        // out-A
        {
            const int pi = i0 + (p >> 3), pj = j0 + (p & 7);
            const long pix = ((long)n*NN + pi)*NN + pj;
            const float4 u4 = *(const float4*)(U + ((long)n*NN + pi)*CC + sc);
            const float4 v4 = *(const float4*)(V + ((long)n*NN + pj)*CC + sc);
            float vv[4];
            vv[0] = accA[pf][0] + u4.x + v4.x + bv.x;
            vv[1] = accA[pf][1] + u4.y + v4.y + bv.y;
            vv[2] = accA[pf][2] + u4.z + v4.z + bv.z;
            vv[3] = accA[pf][3] + u4.w + v4.w + bv.w;
            if (it == jt && pi == pj) {
                const float4 d4  = *(const float4*)(D + ((long)n*NN + pi)*CC + sc);
                const float4 db4 = *(const float4*)(idbias + sc);
                vv[0] += d4.x + db4.x; vv[1] += d4.y + db4.y;
                vv[2] += d4.z + db4.z; vv[3] += d4.w + db4.w;
            }
            const float mv = mask[pix];
            #pragma unroll
            for (int r = 0; r < 4; ++r) vv[r] = leaky(vv[r]) * mv;
            if (outf) *(float4*)(outf + pix*CC + sc) = make_float4(vv[0], vv[1], vv[2], vv[3]);
            else      *(uint2*)(outb + pix*CC + sc) = make_uint2(pkf(vv[0], vv[1]), pkf(vv[2], vv[3]));
        }
        // out-M (mirror tile; disjoint from out-A when it != jt)
        if (it != jt) {
            const int pi = j0 + (p & 7), pj = i0 + (p >> 3);
            const long pix = ((long)n*NN + pi)*NN + pj;
            const float4 u4 = *(const float4*)(U + ((long)n*NN + pi)*CC + sc);
            const float4 v4 = *(const float4*)(V + ((long)n*NN + pj)*CC + sc);
            float vv[4];
            vv[0] = accM[pf][0] + u4.x + v4.x + bv.x;
            vv[1] = accM[pf][1] + u4.y + v4.y + bv.y;
            vv[2] = accM[pf][2] + u4.z + v4.z + bv.z;
            vv[3] = accM[pf][3] + u4.w + v4.w + bv.w;
            const float mv = mask[pix];
            #pragma unroll
            for (int r = 0; r < 4; ++r) vv[r] = leaky(vv[r]) * mv;
            if (outf) *(float4*)(outf + pix*CC + sc) = make_float4(vv[0], vv[1], vv[2], vv[3]);
            else      *(uint2*)(outb + pix*CC + sc) = make_uint2(pkf(vv[0], vv[1]), pkf(vv[2], vv[3]));
        }
    }
}

extern "C" void kernel_launch(void* const* d_in, const int* in_sizes, int n_in,
                              void* d_out, int out_size, void* d_ws, size_t ws_size,
                              hipStream_t stream) {
    const float* x     = (const float*)d_in[0];
    const float* mask  = (const float*)d_in[1];
    const float* w1    = (const float*)d_in[2];
    const float* b1    = (const float*)d_in[3];
    const float* w2    = (const float*)d_in[4];
    const float* b2    = (const float*)d_in[5];
    const float* w3    = (const float*)d_in[6];
    const float* b3    = (const float*)d_in[7];
    const float* coefs = (const float*)d_in[8];
    const float* bias  = (const float*)d_in[9];
    const float* idb   = (const float*)d_in[10];
    float* out = (float*)d_out;
    float* ws  = (float*)d_ws;

    short* hhi    = (short*)(ws + OFF_HHI);
    short* hlo    = (short*)(ws + OFF_HLO);
    short* xn     = (short*)(ws + OFF_XN);
    float* rowsum = ws + OFF_RS;
    float* diag   = ws + OFF_DG;
    short* rcdh   = (short*)(ws + OFF_RCDH);
    short* rcdl   = (short*)(ws + OFF_RCDL);
    float* U      = ws + OFF_U;
    float* V      = ws + OFF_V;
    float* D      = ws + OFF_D;
    short* sb     = (short*)(ws + OFF_SB);

    prep_kernel<<<912, 256, 0, stream>>>(w1, w2, w3, coefs, ws);

    for (int l = 0; l < LL; ++l) {
        mlp_kernel<<<NPOS/64, 256, 0, stream>>>(
            (l == 0) ? x : nullptr, (l == 0) ? nullptr : xn, mask,
            b1 + l*HH, b2 + l*HH, b3 + l*CC,
            sb + (long)l*HH*CC, sb + 24576 + (long)l*HH*HH, sb + 73728 + (long)l*CC*HH,
            hhi, hlo);
        reduce_kernel<<<BB*NN, 256, 0, stream>>>(hhi, hlo, rowsum, diag, rcdh, rcdl);
        uvd_kernel<<<16, 256, 0, stream>>>(rcdh, rcdl,
            sb + 147456 + (long)l*36864, sb + 258048 + (long)l*36864,
            rowsum, diag, coefs, l, U, V, D);
        eq_kernel<<<dim3(136, BB), 256, 0, stream>>>(
            hhi, hlo, mask,
            sb + 98304 + (long)l*CC*CC, sb + 110592 + (long)l*CC*CC,
            sb + 122880 + (long)l*CC*CC, sb + 135168 + (long)l*CC*CC,
            U, V, D, bias + l*CC, idb + l*CC,
            (l == LL-1) ? out : nullptr, (l == LL-1) ? nullptr : xn);
    }
}

// Round 7
// 241.100 us; speedup vs baseline: 1.2582x; 1.2582x over previous
//
#include <hip/hip_runtime.h>

#define BB 8
#define NN 128
#define CC 64
#define LL 3
#define HH 128
#define NEG 0.01f
#define NPOS (BB*NN*NN)   // 131072

typedef __attribute__((ext_vector_type(8))) short shortx8;   // 8 bf16 = 4 VGPRs
typedef __attribute__((ext_vector_type(4))) float f32x4;

// ---- workspace layout (float offsets) ----
#define OFF_HHI   0L          // h bf16: 131072*64 shorts = 4194304 floats
#define OFF_XN    8388608L    // inter-layer x (bf16): 4194304 floats
#define OFF_RS    12582912L   // rowsum fp32 [1024][64]
#define OFF_DG    12648448L   // diag fp32 [1024][64]
#define OFF_RCDH  12713984L   // RCD hi [1024][192] shorts = 98304 floats
#define OFF_RCDL  12812288L
#define OFF_U     12911616L   // [1024][64]
#define OFF_V     12977152L
#define OFF_D     13042688L
#define OFF_SB    13108224L   // bf16 const region (shorts)
// sb short offsets: wb1@0 (L*128*64), wb2@24576 (L*128*128), wb3@73728 (L*64*128),
//   c9h@98304, c9l@110592, c10h@122880, c10l@135168 (each L*64*64, [l][s][d]),
//   Kh@147456, Kl@258048 (each L*192*192, [l][out][k])

__device__ __forceinline__ float leaky(float v) { return v >= 0.f ? v : NEG * v; }

__device__ __forceinline__ short f2bf(float f) {   // RNE float -> bf16
    unsigned u = __builtin_bit_cast(unsigned, f);
    u += 0x7fff + ((u >> 16) & 1);
    return (short)(u >> 16);
}
__device__ __forceinline__ float bf2f(short s) {
    unsigned u = ((unsigned)(unsigned short)s) << 16;
    return __builtin_bit_cast(float, u);
}
__device__ __forceinline__ unsigned pkf(float a, float b) {  // two f32 -> packed bf16x2
    return (unsigned)(unsigned short)f2bf(a) | ((unsigned)(unsigned short)f2bf(b) << 16);
}
__device__ __forceinline__ shortx8 cvt8(const float* p) {    // 8 f32 -> 8 bf16
    float4 f0 = *(const float4*)p, f1 = *(const float4*)(p + 4);
    shortx8 r;
    r[0]=f2bf(f0.x); r[1]=f2bf(f0.y); r[2]=f2bf(f0.z); r[3]=f2bf(f0.w);
    r[4]=f2bf(f1.x); r[5]=f2bf(f1.y); r[6]=f2bf(f1.z); r[7]=f2bf(f1.w);
    return r;
}

// ---------------- prep: bf16 weights, split c9/c10 [s][d], split K-matrix [out][k] ----------------
__global__ void prep_kernel(const float* __restrict__ w1, const float* __restrict__ w2,
                            const float* __restrict__ w3, const float* __restrict__ coefs,
                            float* __restrict__ ws) {
    long idx = (long)blockIdx.x * 256 + threadIdx.x;
    short* sb = (short*)(ws + OFF_SB);
    if (idx < 24576) {                       // wb1[l][h][c]
        sb[idx] = f2bf(w1[idx]);
    } else if (idx < 73728) {                // wb2[l][h][k]
        sb[idx] = f2bf(w2[idx - 24576]);
    } else if (idx < 98304) {                // wb3[l][c][k]
        sb[idx] = f2bf(w3[idx - 73728]);
    } else if (idx < 110592) {               // c9 hi/lo [l][s][d]
        long r = idx - 98304; int l = (int)(r / 4096); int q = (int)(r % 4096);
        int s = q >> 6, d = q & 63;
        float v = coefs[(((long)l*CC + d)*CC + s)*15 + 9];
        short hi = f2bf(v);
        sb[98304 + r]  = hi;
        sb[110592 + r] = f2bf(v - bf2f(hi));
    } else if (idx < 122880) {               // c10 hi/lo [l][s][d]
        long r = idx - 110592; int l = (int)(r / 4096); int q = (int)(r % 4096);
        int s = q >> 6, d = q & 63;
        float v = coefs[(((long)l*CC + d)*CC + s)*15 + 10];
        short hi = f2bf(v);
        sb[122880 + r] = hi;
        sb[135168 + r] = f2bf(v - bf2f(hi));
    } else if (idx < 233472) {               // Kbig hi/lo [l][out 192][k 192]
        long r = idx - 122880;
        int l = (int)(r / 36864); int q = (int)(r % 36864);
        int o = q / 192, k = q % 192;
        int wo = o >> 6, s = o & 63, wk = k >> 6, d = k & 63;
        const int sel[3][3] = {{5,6,11},{7,8,12},{3,2,0}};
        float v = coefs[(((long)l*CC + d)*CC + s)*15 + sel[wo][wk]];
        short hi = f2bf(v);
        sb[147456 + r] = hi;
        sb[258048 + r] = f2bf(v - bf2f(hi));
    }
}

// ---------------- MFMA fused 3-stage MLP (round-5 structure, single-bf16 h) ----------------
// Swapped operands (W = A-frag from global/L2, x = B-frag from LDS).
// LDS: h1@[0,16K), h2@[16K,32K), xt@[16K,24K) (aliases h2 -- xt dead before h2 written).
// h1/h2: 64 pos x 128 ch bf16, 256B rows, XOR swizzle (p&15)<<4 (16 slots).
// xt: 64 pos x 64 ch bf16, 128B rows, XOR swizzle (p&7)<<4.
__global__ __launch_bounds__(256, 4) void mlp_kernel(
    const float* __restrict__ xf, const short* __restrict__ xb,
    const float* __restrict__ mask,
    const float* __restrict__ b1, const float* __restrict__ b2, const float* __restrict__ b3,
    const short* __restrict__ wb1, const short* __restrict__ wb2, const short* __restrict__ wb3,
    short* __restrict__ hout)
{
    __shared__ __align__(16) char lds[32768];
    const int t = threadIdx.x;
    const int lane = t & 63;
    const int w = t >> 6;
    const int arow = lane & 15;
    const int kgrp = lane >> 4;
    const long pos0 = (long)blockIdx.x * 64;
    const int XT = 16384;

    // ---- stage x -> bf16 LDS tile ----
    {
        const int row = t >> 2, q = t & 3;
        const long off = (pos0 + row)*CC + q*16;
        shortx8 v0, v1;
        if (xb) { v0 = *(const shortx8*)(xb + off); v1 = *(const shortx8*)(xb + off + 8); }
        else    { v0 = cvt8(xf + off);              v1 = cvt8(xf + off + 8); }
        const int swz = (row & 7) << 4;
        *(shortx8*)(&lds[XT + row*128 + ((q*32)      ^ swz)]) = v0;
        *(shortx8*)(&lds[XT + row*128 + ((q*32 + 16) ^ swz)]) = v1;
    }
    __syncthreads();

    // ---- stage 1: 128 outs; wave w -> [w*32, w*32+32) ----
    {
        f32x4 acc[2][4];
        #pragma unroll
        for (int of = 0; of < 2; ++of)
            #pragma unroll
            for (int pf = 0; pf < 4; ++pf) acc[of][pf] = (f32x4){0.f,0.f,0.f,0.f};
        #pragma unroll
        for (int kk = 0; kk < 2; ++kk) {
            shortx8 bx[4];
            #pragma unroll
            for (int pf = 0; pf < 4; ++pf) {
                const int p = pf*16 + arow;
                bx[pf] = *(const shortx8*)(&lds[XT + p*128 + ((kk*64 + kgrp*16) ^ ((p & 7) << 4))]);
            }
            #pragma unroll
            for (int of = 0; of < 2; ++of) {
                const shortx8 a = *(const shortx8*)(wb1 + (long)(w*32 + of*16 + arow)*CC + kk*32 + kgrp*8);
                #pragma unroll
                for (int pf = 0; pf < 4; ++pf)
                    acc[of][pf] = __builtin_amdgcn_mfma_f32_16x16x32_bf16(a, bx[pf], acc[of][pf], 0, 0, 0);
            }
        }
        #pragma unroll
        for (int of = 0; of < 2; ++of) {
            const int o0 = w*32 + of*16 + kgrp*4;
            const float4 bv = *(const float4*)(b1 + o0);
            #pragma unroll
            for (int pf = 0; pf < 4; ++pf) {
                const int p = pf*16 + arow;
                unsigned u0 = pkf(leaky(acc[of][pf][0] + bv.x), leaky(acc[of][pf][1] + bv.y));
                unsigned u1 = pkf(leaky(acc[of][pf][2] + bv.z), leaky(acc[of][pf][3] + bv.w));
                *(uint2*)(&lds[p*256 + ((o0*2) ^ ((p & 15) << 4))]) = make_uint2(u0, u1);
            }
        }
    }
    __syncthreads();

    // ---- stage 2: 128 outs ----
    {
        f32x4 acc[2][4];
        #pragma unroll
        for (int of = 0; of < 2; ++of)
            #pragma unroll
            for (int pf = 0; pf < 4; ++pf) acc[of][pf] = (f32x4){0.f,0.f,0.f,0.f};
        #pragma unroll
        for (int kk = 0; kk < 4; ++kk) {
            shortx8 bx[4];
            #pragma unroll
            for (int pf = 0; pf < 4; ++pf) {
                const int p = pf*16 + arow;
                bx[pf] = *(const shortx8*)(&lds[p*256 + ((kk*64 + kgrp*16) ^ ((p & 15) << 4))]);
            }
            #pragma unroll
            for (int of = 0; of < 2; ++of) {
                const shortx8 a = *(const shortx8*)(wb2 + (long)(w*32 + of*16 + arow)*HH + kk*32 + kgrp*8);
                #pragma unroll
                for (int pf = 0; pf < 4; ++pf)
                    acc[of][pf] = __builtin_amdgcn_mfma_f32_16x16x32_bf16(a, bx[pf], acc[of][pf], 0, 0, 0);
            }
        }
        __syncthreads();   // h1 reads done; h2 region (aliases xt) now writable
        #pragma unroll
        for (int of = 0; of < 2; ++of) {
            const int o0 = w*32 + of*16 + kgrp*4;
            const float4 bv = *(const float4*)(b2 + o0);
            #pragma unroll
            for (int pf = 0; pf < 4; ++pf) {
                const int p = pf*16 + arow;
                unsigned u0 = pkf(leaky(acc[of][pf][0] + bv.x), leaky(acc[of][pf][1] + bv.y));
                unsigned u1 = pkf(leaky(acc[of][pf][2] + bv.z), leaky(acc[of][pf][3] + bv.w));
                *(uint2*)(&lds[16384 + p*256 + ((o0*2) ^ ((p & 15) << 4))]) = make_uint2(u0, u1);
            }
        }
    }
    __syncthreads();

    // ---- stage 3: 64 outs; direct bf16 global store ----
    {
        f32x4 acc[4];
        #pragma unroll
        for (int pf = 0; pf < 4; ++pf) acc[pf] = (f32x4){0.f,0.f,0.f,0.f};
        #pragma unroll
        for (int kk = 0; kk < 4; ++kk) {
            const shortx8 a = *(const shortx8*)(wb3 + (long)(w*16 + arow)*HH + kk*32 + kgrp*8);
            #pragma unroll
            for (int pf = 0; pf < 4; ++pf) {
                const int p = pf*16 + arow;
                const shortx8 bx = *(const shortx8*)(&lds[16384 + p*256 + ((kk*64 + kgrp*16) ^ ((p & 15) << 4))]);
                acc[pf] = __builtin_amdgcn_mfma_f32_16x16x32_bf16(a, bx, acc[pf], 0, 0, 0);
            }
        }
        const int o0 = w*16 + kgrp*4;
        const float4 bv = *(const float4*)(b3 + o0);
        #pragma unroll
        for (int pf = 0; pf < 4; ++pf) {
            const int p = pf*16 + arow;
            const long pos = pos0 + p;
            const float mv = mask[pos];
            float v0 = leaky(acc[pf][0] + bv.x) * mv;
            float v1 = leaky(acc[pf][1] + bv.y) * mv;
            float v2 = leaky(acc[pf][2] + bv.z) * mv;
            float v3 = leaky(acc[pf][3] + bv.w) * mv;
            *(uint2*)(hout + pos*CC + o0) = make_uint2(pkf(v0, v1), pkf(v2, v3));
        }
    }
}

// ---------------- vectorized reductions: 16B loads, colsum/rowsum/diag ----------------
__global__ __launch_bounds__(256) void reduce_kernel(const short* __restrict__ h,
                                                     float* __restrict__ rowsum,
                                                     float* __restrict__ diag,
                                                     short* __restrict__ rcdh,
                                                     short* __restrict__ rcdl) {
    const int br = blockIdx.x;            // n*128 + r
    const int n = br >> 7, r = br & 127;
    const int t = threadIdx.x;
    const int c8 = (t & 7) * 8;           // 8-channel slice
    const int g = t >> 3;                 // 32 groups
    __shared__ float red[32][64];
    const long rowbase = ((long)(n*NN + r) * NN) * CC;

    // row pass: sum over j
    {
        float s[8];
        #pragma unroll
        for (int e = 0; e < 8; ++e) s[e] = 0.f;
        for (int j = g; j < NN; j += 32) {
            const shortx8 vh = *(const shortx8*)(h + rowbase + (long)j*CC + c8);
            #pragma unroll
            for (int e = 0; e < 8; ++e) s[e] += bf2f(vh[e]);
        }
        #pragma unroll
        for (int e = 0; e < 8; ++e) red[g][c8 + e] = s[e];
    }
    __syncthreads();
    if (t < 64) {
        float rs = 0.f;
        #pragma unroll
        for (int k = 0; k < 32; ++k) rs += red[k][t];
        rowsum[(long)br*CC + t] = rs;
        short hh = f2bf(rs);
        rcdh[(long)br*192 + 64 + t] = hh;
        rcdl[(long)br*192 + 64 + t] = f2bf(rs - bf2f(hh));
    }
    __syncthreads();

    // col pass: sum over i
    {
        const long colbase = ((long)n*NN*NN + r) * CC;
        float s[8];
        #pragma unroll
        for (int e = 0; e < 8; ++e) s[e] = 0.f;
        for (int i = g; i < NN; i += 32) {
            const shortx8 vh = *(const shortx8*)(h + colbase + (long)i*NN*CC + c8);
            #pragma unroll
            for (int e = 0; e < 8; ++e) s[e] += bf2f(vh[e]);
        }
        #pragma unroll
        for (int e = 0; e < 8; ++e) red[g][c8 + e] = s[e];
    }
    __syncthreads();
    if (t < 64) {
        float cs = 0.f;
        #pragma unroll
        for (int k = 0; k < 32; ++k) cs += red[k][t];
        short hh = f2bf(cs);
        rcdh[(long)br*192 + t] = hh;
        rcdl[(long)br*192 + t] = f2bf(cs - bf2f(hh));
        const float dg = bf2f(h[rowbase + (long)r*CC + t]);
        diag[(long)br*CC + t] = dg;
        short hd = f2bf(dg);
        rcdh[(long)br*192 + 128 + t] = hd;
        rcdl[(long)br*192 + 128 + t] = f2bf(dg - bf2f(hd));
    }
}

// ---------------- U/V/D via MFMA, with trace/total biases computed in-block ----------------
__global__ __launch_bounds__(256) void uvd_kernel(
    const short* __restrict__ rcdh, const short* __restrict__ rcdl,
    const short* __restrict__ kh, const short* __restrict__ kl,
    const float* __restrict__ rowsum, const float* __restrict__ diag,
    const float* __restrict__ coefs, int layer,
    float* __restrict__ U, float* __restrict__ V, float* __restrict__ D)
{
    __shared__ float ra[4][64], rb[4][64];
    __shared__ float ub[64], db[64];
    const int t = threadIdx.x, lane = t & 63, w = t >> 6;
    const int arow = lane & 15, kgrp = lane >> 4;
    const int r0 = blockIdx.x * 64;
    const int nb = r0 >> 7;

    // ---- in-block trace/total -> ub/db ----
    {
        const int c = t & 63, g = t >> 6;
        float a = 0.f, b = 0.f;
        for (int i = g; i < NN; i += 4) {
            a += rowsum[((long)nb*NN + i)*CC + c];
            b += diag[((long)nb*NN + i)*CC + c];
        }
        ra[g][c] = a; rb[g][c] = b;
    }
    __syncthreads();
    if (t < 128) {
        const int which = t >> 6, s = t & 63;
        const float* cf = coefs + (long)layer*CC*CC*15;
        float acc = 0.f;
        for (int d = 0; d < CC; ++d) {
            const float tt = ra[0][d] + ra[1][d] + ra[2][d] + ra[3][d];
            const float tr = rb[0][d] + rb[1][d] + rb[2][d] + rb[3][d];
            const float* cds = cf + ((long)d*CC + s)*15;
            if (which == 0) acc += cds[13]*tr + cds[14]*tt;
            else            acc += cds[1]*tr + cds[4]*tt;
        }
        if (which == 0) ub[s] = acc; else db[s] = acc;
    }
    __syncthreads();

    f32x4 acc[3][4];
    #pragma unroll
    for (int o = 0; o < 3; ++o)
        #pragma unroll
        for (int pf = 0; pf < 4; ++pf) acc[o][pf] = (f32x4){0.f,0.f,0.f,0.f};
    #pragma unroll
    for (int kk = 0; kk < 6; ++kk) {
        shortx8 bh[4], bl[4];
        #pragma unroll
        for (int pf = 0; pf < 4; ++pf) {
            const long off = (long)(r0 + pf*16 + arow)*192 + kk*32 + kgrp*8;
            bh[pf] = *(const shortx8*)(rcdh + off);
            bl[pf] = *(const shortx8*)(rcdl + off);
        }
        #pragma unroll
        for (int o = 0; o < 3; ++o) {
            const long aoff = (long)((w*3 + o)*16 + arow)*192 + kk*32 + kgrp*8;
            const shortx8 ah = *(const shortx8*)(kh + aoff);
            const shortx8 al = *(const shortx8*)(kl + aoff);
            #pragma unroll
            for (int pf = 0; pf < 4; ++pf) {
                acc[o][pf] = __builtin_amdgcn_mfma_f32_16x16x32_bf16(ah, bh[pf], acc[o][pf], 0, 0, 0);
                acc[o][pf] = __builtin_amdgcn_mfma_f32_16x16x32_bf16(ah, bl[pf], acc[o][pf], 0, 0, 0);
                acc[o][pf] = __builtin_amdgcn_mfma_f32_16x16x32_bf16(al, bh[pf], acc[o][pf], 0, 0, 0);
            }
        }
    }
    #pragma unroll
    for (int o = 0; o < 3; ++o) {
        const int o16 = (w*3 + o)*16;
        const int o0 = o16 + kgrp*4;
        #pragma unroll
        for (int pf = 0; pf < 4; ++pf) {
            const long rr = r0 + pf*16 + arow;
            float4 a = make_float4(acc[o][pf][0], acc[o][pf][1], acc[o][pf][2], acc[o][pf][3]);
            if (o16 < 64) {
                a.x += ub[o0]; a.y += ub[o0+1]; a.z += ub[o0+2]; a.w += ub[o0+3];
                *(float4*)(U + rr*CC + o0) = a;
            } else if (o16 < 128) {
                *(float4*)(V + rr*CC + (o0 - 64)) = a;
            } else {
                const int q = o0 - 128;
                a.x += db[q]; a.y += db[q+1]; a.z += db[q+2]; a.w += db[q+3];
                *(float4*)(D + rr*CC + q) = a;
            }
        }
    }
}

// ---------------- Eq2to2: symmetric pair-block, bf16 h, split-c only ----------------
__global__ __launch_bounds__(256, 4) void eq_kernel(
    const short* __restrict__ h, const float* __restrict__ mask,
    const short* __restrict__ c9h, const short* __restrict__ c9l,
    const short* __restrict__ c10h, const short* __restrict__ c10l,
    const float* __restrict__ U, const float* __restrict__ V, const float* __restrict__ D,
    const float* __restrict__ bias, const float* __restrict__ idbias,
    float* __restrict__ outf, short* __restrict__ outb)
{
    __shared__ __align__(16) char lds[16384];
    const int t = threadIdx.x, lane = t & 63, w = t >> 6;
    const int arow = lane & 15, kgrp = lane >> 4;
    const int n = blockIdx.y;
    const int pr = blockIdx.x;
    int it = (int)((sqrtf(8.f*pr + 1.f) - 1.f)*0.5f);
    while ((it+1)*(it+2)/2 <= pr) ++it;
    while (it*(it+1)/2 > pr) --it;
    const int jt = pr - it*(it+1)/2;      // jt <= it
    const int i0 = it*8, j0 = jt*8;
    const int s0 = w*16;

    // ---- prefetch c9/c10 fragments ----
    shortx8 A9h[2], A9l[2], A10h[2], A10l[2];
    #pragma unroll
    for (int kk = 0; kk < 2; ++kk) {
        const long co = (long)(s0 + arow)*CC + kk*32 + kgrp*8;
        A9h[kk]  = *(const shortx8*)(c9h  + co);
        A9l[kk]  = *(const shortx8*)(c9l  + co);
        A10h[kk] = *(const shortx8*)(c10h + co);
        A10l[kk] = *(const shortx8*)(c10l + co);
    }

    // ---- stage both tiles, coalesced 32B loads, swizzled 16B ds_writes ----
    {
        const int row = t >> 2, q = t & 3;
        const long posA = ((long)n*NN + i0 + (row >> 3))*NN + (j0 + (row & 7));
        const long posM = ((long)n*NN + j0 + (row & 7))*NN + (i0 + (row >> 3));
        const short* sA = h + posA*CC + q*16;
        const short* sM = h + posM*CC + q*16;
        shortx8 v0 = *(const shortx8*)(sA);
        shortx8 v1 = *(const shortx8*)(sA + 8);
        shortx8 v4 = *(const shortx8*)(sM);
        shortx8 v5 = *(const shortx8*)(sM + 8);
        const int swz = (row & 7) << 4;
        const int d0 = row*128 + ((q*32) ^ swz);
        const int d1 = row*128 + ((q*32 + 16) ^ swz);
        *(shortx8*)(&lds[d0]) = v0;          *(shortx8*)(&lds[d1]) = v1;
        *(shortx8*)(&lds[8192 + d0]) = v4;   *(shortx8*)(&lds[8192 + d1]) = v5;
    }
    __syncthreads();

    f32x4 accA[4], accM[4];
    #pragma unroll
    for (int pf = 0; pf < 4; ++pf) { accA[pf] = (f32x4){0.f,0.f,0.f,0.f}; accM[pf] = (f32x4){0.f,0.f,0.f,0.f}; }

    #pragma unroll
    for (int kk = 0; kk < 2; ++kk) {
        #pragma unroll
        for (int pf = 0; pf < 4; ++pf) {
            const int p = pf*16 + arow;
            const int off = (kk*64 + kgrp*16) ^ ((p & 7) << 4);
            const shortx8 Ah = *(const shortx8*)(&lds[p*128 + off]);
            const shortx8 Mh = *(const shortx8*)(&lds[8192 + p*128 + off]);
            accA[pf] = __builtin_amdgcn_mfma_f32_16x16x32_bf16(A9h[kk],  Ah, accA[pf], 0, 0, 0);
            accA[pf] = __builtin_amdgcn_mfma_f32_16x16x32_bf16(A9l[kk],  Ah, accA[pf], 0, 0, 0);
            accA[pf] = __builtin_amdgcn_mfma_f32_16x16x32_bf16(A10h[kk], Mh, accA[pf], 0, 0, 0);
            accA[pf] = __builtin_amdgcn_mfma_f32_16x16x32_bf16(A10l[kk], Mh, accA[pf], 0, 0, 0);
            accM[pf] = __builtin_amdgcn_mfma_f32_16x16x32_bf16(A9h[kk],  Mh, accM[pf], 0, 0, 0);
            accM[pf] = __builtin_amdgcn_mfma_f32_16x16x32_bf16(A9l[kk],  Mh, accM[pf], 0, 0, 0);
            accM[pf] = __builtin_amdgcn_mfma_f32_16x16x32_bf16(A10h[kk], Ah, accM[pf], 0, 0, 0);
            accM[pf] = __builtin_amdgcn_mfma_f32_16x16x32_bf16(A10l[kk], Ah, accM[pf], 0, 0, 0);
        }
    }

    const int sc = s0 + kgrp*4;
    const float4 bv = *(const float4*)(bias + sc);
    #pragma unroll
    for (int pf = 0; pf < 4; ++pf) {
        const int p = pf*16 + arow;
        // out-A
        {
            const int pi = i0 + (p >> 3), pj = j0 + (p & 7);
            const long pix = ((long)n*NN + pi)*NN + pj;
            const float4 u4 = *(const float4*)(U + ((long)n*NN + pi)*CC + sc);
            const float4 v4 = *(const float4*)(V + ((long)n*NN + pj)*CC + sc);
            float vv[4];
            vv[0] = accA[pf][0] + u4.x + v4.x + bv.x;
            vv[1] = accA[pf][1] + u4.y + v4.y + bv.y;
            vv[2] = accA[pf][2] + u4.z + v4.z + bv.z;
            vv[3] = accA[pf][3] + u4.w + v4.w + bv.w;
            if (it == jt && pi == pj) {
                const float4 d4  = *(const float4*)(D + ((long)n*NN + pi)*CC + sc);
                const float4 db4 = *(const float4*)(idbias + sc);
                vv[0] += d4.x + db4.x; vv[1] += d4.y + db4.y;
                vv[2] += d4.z + db4.z; vv[3] += d4.w + db4.w;
            }
            const float mv = mask[pix];
            #pragma unroll
            for (int r = 0; r < 4; ++r) vv[r] = leaky(vv[r]) * mv;
            if (outf) *(float4*)(outf + pix*CC + sc) = make_float4(vv[0], vv[1], vv[2], vv[3]);
            else      *(uint2*)(outb + pix*CC + sc) = make_uint2(pkf(vv[0], vv[1]), pkf(vv[2], vv[3]));
        }
        // out-M (mirror tile; disjoint when it != jt)
        if (it != jt) {
            const int pi = j0 + (p & 7), pj = i0 + (p >> 3);
            const long pix = ((long)n*NN + pi)*NN + pj;
            const float4 u4 = *(const float4*)(U + ((long)n*NN + pi)*CC + sc);
            const float4 v4 = *(const float4*)(V + ((long)n*NN + pj)*CC + sc);
            float vv[4];
            vv[0] = accM[pf][0] + u4.x + v4.x + bv.x;
            vv[1] = accM[pf][1] + u4.y + v4.y + bv.y;
            vv[2] = accM[pf][2] + u4.z + v4.z + bv.z;
            vv[3] = accM[pf][3] + u4.w + v4.w + bv.w;
            const float mv = mask[pix];
            #pragma unroll
            for (int r = 0; r < 4; ++r) vv[r] = leaky(vv[r]) * mv;
            if (outf) *(float4*)(outf + pix*CC + sc) = make_float4(vv[0], vv[1], vv[2], vv[3]);
            else      *(uint2*)(outb + pix*CC + sc) = make_uint2(pkf(vv[0], vv[1]), pkf(vv[2], vv[3]));
        }
    }
}

extern "C" void kernel_launch(void* const* d_in, const int* in_sizes, int n_in,
                              void* d_out, int out_size, void* d_ws, size_t ws_size,
                              hipStream_t stream) {
    const float* x     = (const float*)d_in[0];
    const float* mask  = (const float*)d_in[1];
    const float* w1    = (const float*)d_in[2];
    const float* b1    = (const float*)d_in[3];
    const float* w2    = (const float*)d_in[4];
    const float* b2    = (const float*)d_in[5];
    const float* w3    = (const float*)d_in[6];
    const float* b3    = (const float*)d_in[7];
    const float* coefs = (const float*)d_in[8];
    const float* bias  = (const float*)d_in[9];
    const float* idb   = (const float*)d_in[10];
    float* out = (float*)d_out;
    float* ws  = (float*)d_ws;

    short* hh     = (short*)(ws + OFF_HHI);
    short* xn     = (short*)(ws + OFF_XN);
    float* rowsum = ws + OFF_RS;
    float* diag   = ws + OFF_DG;
    short* rcdh   = (short*)(ws + OFF_RCDH);
    short* rcdl   = (short*)(ws + OFF_RCDL);
    float* U      = ws + OFF_U;
    float* V      = ws + OFF_V;
    float* D      = ws + OFF_D;
    short* sb     = (short*)(ws + OFF_SB);

    prep_kernel<<<912, 256, 0, stream>>>(w1, w2, w3, coefs, ws);

    for (int l = 0; l < LL; ++l) {
        mlp_kernel<<<NPOS/64, 256, 0, stream>>>(
            (l == 0) ? x : nullptr, (l == 0) ? nullptr : xn, mask,
            b1 + l*HH, b2 + l*HH, b3 + l*CC,
            sb + (long)l*HH*CC, sb + 24576 + (long)l*HH*HH, sb + 73728 + (long)l*CC*HH,
            hh);
        reduce_kernel<<<BB*NN, 256, 0, stream>>>(hh, rowsum, diag, rcdh, rcdl);
        uvd_kernel<<<16, 256, 0, stream>>>(rcdh, rcdl,
            sb + 147456 + (long)l*36864, sb + 258048 + (long)l*36864,
            rowsum, diag, coefs, l, U, V, D);
        eq_kernel<<<dim3(136, BB), 256, 0, stream>>>(
            hh, mask,
            sb + 98304 + (long)l*CC*CC, sb + 110592 + (long)l*CC*CC,
            sb + 122880 + (long)l*CC*CC, sb + 135168 + (long)l*CC*CC,
            U, V, D, bias + l*CC, idb + l*CC,
            (l == LL-1) ? out : nullptr, (l == LL-1) ? nullptr : xn);
    }
}

// Round 8
// 238.948 us; speedup vs baseline: 1.2695x; 1.0090x over previous
//
#include <hip/hip_runtime.h>
#include <hip/hip_bf16.h>

#define BB 8
#define NN 128
#define CC 64
#define LL 3
#define HH 128
#define NEG 0.01f
#define NPOS (BB*NN*NN)   // 131072

typedef __attribute__((ext_vector_type(8))) short shortx8;   // 8 bf16 = 4 VGPRs
typedef __attribute__((ext_vector_type(4))) float f32x4;

// ---- workspace layout (float offsets) ----
#define OFF_HHI   0L          // h bf16: 131072*64 shorts = 4194304 floats
#define OFF_XN    8388608L    // inter-layer x (bf16): 4194304 floats
#define OFF_RS    12582912L   // rowsum fp32 [1024][64]
#define OFF_DG    12648448L   // diag fp32 [1024][64]
#define OFF_RCDH  12713984L   // RCD hi [1024][192] shorts = 98304 floats
#define OFF_RCDL  12812288L
#define OFF_U     12911616L   // [1024][64]
#define OFF_V     12977152L
#define OFF_D     13042688L
#define OFF_SB    13108224L   // bf16 const region (shorts)
// sb short offsets: wb1@0 (L*128*64), wb2@24576 (L*128*128), wb3@73728 (L*64*128),
//   c9h@98304, c9l@110592, c10h@122880, c10l@135168 (each L*64*64, [l][s][d]),
//   Kh@147456, Kl@258048 (each L*192*192, [l][out][k])

__device__ __forceinline__ float leaky(float v) { return v >= 0.f ? v : NEG * v; }

// float -> bf16 via compiler cast (lowers to HW cvt; pairs fuse to v_cvt_pk_bf16_f32)
__device__ __forceinline__ short f2bf(float f) {
    return (short)__bfloat16_as_ushort(__float2bfloat16(f));
}
__device__ __forceinline__ float bf2f(short s) {
    unsigned u = ((unsigned)(unsigned short)s) << 16;
    return __builtin_bit_cast(float, u);
}
__device__ __forceinline__ unsigned pkf(float a, float b) {  // two f32 -> packed bf16x2
    return (unsigned)(unsigned short)f2bf(a) | ((unsigned)(unsigned short)f2bf(b) << 16);
}
__device__ __forceinline__ shortx8 cvt8(const float* p) {    // 8 f32 -> 8 bf16
    float4 f0 = *(const float4*)p, f1 = *(const float4*)(p + 4);
    shortx8 r;
    r[0]=f2bf(f0.x); r[1]=f2bf(f0.y); r[2]=f2bf(f0.z); r[3]=f2bf(f0.w);
    r[4]=f2bf(f1.x); r[5]=f2bf(f1.y); r[6]=f2bf(f1.z); r[7]=f2bf(f1.w);
    return r;
}

// ---------------- prep: bf16 weights, split c9/c10 [s][d], split K-matrix [out][k] ----------------
__global__ void prep_kernel(const float* __restrict__ w1, const float* __restrict__ w2,
                            const float* __restrict__ w3, const float* __restrict__ coefs,
                            float* __restrict__ ws) {
    long idx = (long)blockIdx.x * 256 + threadIdx.x;
    short* sb = (short*)(ws + OFF_SB);
    if (idx < 24576) {                       // wb1[l][h][c]
        sb[idx] = f2bf(w1[idx]);
    } else if (idx < 73728) {                // wb2[l][h][k]
        sb[idx] = f2bf(w2[idx - 24576]);
    } else if (idx < 98304) {                // wb3[l][c][k]
        sb[idx] = f2bf(w3[idx - 73728]);
    } else if (idx < 110592) {               // c9 hi/lo [l][s][d]
        long r = idx - 98304; int l = (int)(r / 4096); int q = (int)(r % 4096);
        int s = q >> 6, d = q & 63;
        float v = coefs[(((long)l*CC + d)*CC + s)*15 + 9];
        short hi = f2bf(v);
        sb[98304 + r]  = hi;
        sb[110592 + r] = f2bf(v - bf2f(hi));
    } else if (idx < 122880) {               // c10 hi/lo [l][s][d]
        long r = idx - 110592; int l = (int)(r / 4096); int q = (int)(r % 4096);
        int s = q >> 6, d = q & 63;
        float v = coefs[(((long)l*CC + d)*CC + s)*15 + 10];
        short hi = f2bf(v);
        sb[122880 + r] = hi;
        sb[135168 + r] = f2bf(v - bf2f(hi));
    } else if (idx < 233472) {               // Kbig hi/lo [l][out 192][k 192]
        long r = idx - 122880;
        int l = (int)(r / 36864); int q = (int)(r % 36864);
        int o = q / 192, k = q % 192;
        int wo = o >> 6, s = o & 63, wk = k >> 6, d = k & 63;
        const int sel[3][3] = {{5,6,11},{7,8,12},{3,2,0}};
        float v = coefs[(((long)l*CC + d)*CC + s)*15 + sel[wo][wk]];
        short hi = f2bf(v);
        sb[147456 + r] = hi;
        sb[258048 + r] = f2bf(v - bf2f(hi));
    }
}

// ---------------- MFMA fused 3-stage MLP (single-bf16 h) ----------------
// Swapped operands (W = A-frag from global/L2, x = B-frag from LDS).
// LDS: h1@[0,16K), h2@[16K,32K), xt@[16K,24K) (aliases h2 -- xt dead before h2 written).
__global__ __launch_bounds__(256, 5) void mlp_kernel(
    const float* __restrict__ xf, const short* __restrict__ xb,
    const float* __restrict__ mask,
    const float* __restrict__ b1, const float* __restrict__ b2, const float* __restrict__ b3,
    const short* __restrict__ wb1, const short* __restrict__ wb2, const short* __restrict__ wb3,
    short* __restrict__ hout)
{
    __shared__ __align__(16) char lds[32768];
    const int t = threadIdx.x;
    const int lane = t & 63;
    const int w = t >> 6;
    const int arow = lane & 15;
    const int kgrp = lane >> 4;
    const long pos0 = (long)blockIdx.x * 64;
    const int XT = 16384;

    // ---- stage x -> bf16 LDS tile ----
    {
        const int row = t >> 2, q = t & 3;
        const long off = (pos0 + row)*CC + q*16;
        shortx8 v0, v1;
        if (xb) { v0 = *(const shortx8*)(xb + off); v1 = *(const shortx8*)(xb + off + 8); }
        else    { v0 = cvt8(xf + off);              v1 = cvt8(xf + off + 8); }
        const int swz = (row & 7) << 4;
        *(shortx8*)(&lds[XT + row*128 + ((q*32)      ^ swz)]) = v0;
        *(shortx8*)(&lds[XT + row*128 + ((q*32 + 16) ^ swz)]) = v1;
    }
    __syncthreads();

    // ---- stage 1: 128 outs; wave w -> [w*32, w*32+32) ----
    {
        f32x4 acc[2][4];
        #pragma unroll
        for (int of = 0; of < 2; ++of)
            #pragma unroll
            for (int pf = 0; pf < 4; ++pf) acc[of][pf] = (f32x4){0.f,0.f,0.f,0.f};
        #pragma unroll
        for (int kk = 0; kk < 2; ++kk) {
            shortx8 bx[4];
            #pragma unroll
            for (int pf = 0; pf < 4; ++pf) {
                const int p = pf*16 + arow;
                bx[pf] = *(const shortx8*)(&lds[XT + p*128 + ((kk*64 + kgrp*16) ^ ((p & 7) << 4))]);
            }
            #pragma unroll
            for (int of = 0; of < 2; ++of) {
                const shortx8 a = *(const shortx8*)(wb1 + (long)(w*32 + of*16 + arow)*CC + kk*32 + kgrp*8);
                #pragma unroll
                for (int pf = 0; pf < 4; ++pf)
                    acc[of][pf] = __builtin_amdgcn_mfma_f32_16x16x32_bf16(a, bx[pf], acc[of][pf], 0, 0, 0);
            }
        }
        #pragma unroll
        for (int of = 0; of < 2; ++of) {
            const int o0 = w*32 + of*16 + kgrp*4;
            const float4 bv = *(const float4*)(b1 + o0);
            #pragma unroll
            for (int pf = 0; pf < 4; ++pf) {
                const int p = pf*16 + arow;
                unsigned u0 = pkf(leaky(acc[of][pf][0] + bv.x), leaky(acc[of][pf][1] + bv.y));
                unsigned u1 = pkf(leaky(acc[of][pf][2] + bv.z), leaky(acc[of][pf][3] + bv.w));
                *(uint2*)(&lds[p*256 + ((o0*2) ^ ((p & 15) << 4))]) = make_uint2(u0, u1);
            }
        }
    }
    __syncthreads();

    // ---- stage 2: 128 outs ----
    {
        f32x4 acc[2][4];
        #pragma unroll
        for (int of = 0; of < 2; ++of)
            #pragma unroll
            for (int pf = 0; pf < 4; ++pf) acc[of][pf] = (f32x4){0.f,0.f,0.f,0.f};
        #pragma unroll
        for (int kk = 0; kk < 4; ++kk) {
            shortx8 bx[4];
            #pragma unroll
            for (int pf = 0; pf < 4; ++pf) {
                const int p = pf*16 + arow;
                bx[pf] = *(const shortx8*)(&lds[p*256 + ((kk*64 + kgrp*16) ^ ((p & 15) << 4))]);
            }
            #pragma unroll
            for (int of = 0; of < 2; ++of) {
                const shortx8 a = *(const shortx8*)(wb2 + (long)(w*32 + of*16 + arow)*HH + kk*32 + kgrp*8);
                #pragma unroll
                for (int pf = 0; pf < 4; ++pf)
                    acc[of][pf] = __builtin_amdgcn_mfma_f32_16x16x32_bf16(a, bx[pf], acc[of][pf], 0, 0, 0);
            }
        }
        __syncthreads();   // h1 + xt reads done; h2 region (aliases xt) now writable
        #pragma unroll
        for (int of = 0; of < 2; ++of) {
            const int o0 = w*32 + of*16 + kgrp*4;
            const float4 bv = *(const float4*)(b2 + o0);
            #pragma unroll
            for (int pf = 0; pf < 4; ++pf) {
                const int p = pf*16 + arow;
                unsigned u0 = pkf(leaky(acc[of][pf][0] + bv.x), leaky(acc[of][pf][1] + bv.y));
                unsigned u1 = pkf(leaky(acc[of][pf][2] + bv.z), leaky(acc[of][pf][3] + bv.w));
                *(uint2*)(&lds[16384 + p*256 + ((o0*2) ^ ((p & 15) << 4))]) = make_uint2(u0, u1);
            }
        }
    }
    __syncthreads();

    // ---- stage 3: 64 outs; direct bf16 global store ----
    {
        f32x4 acc[4];
        #pragma unroll
        for (int pf = 0; pf < 4; ++pf) acc[pf] = (f32x4){0.f,0.f,0.f,0.f};
        #pragma unroll
        for (int kk = 0; kk < 4; ++kk) {
            const shortx8 a = *(const shortx8*)(wb3 + (long)(w*16 + arow)*HH + kk*32 + kgrp*8);
            #pragma unroll
            for (int pf = 0; pf < 4; ++pf) {
                const int p = pf*16 + arow;
                const shortx8 bx = *(const shortx8*)(&lds[16384 + p*256 + ((kk*64 + kgrp*16) ^ ((p & 15) << 4))]);
                acc[pf] = __builtin_amdgcn_mfma_f32_16x16x32_bf16(a, bx, acc[pf], 0, 0, 0);
            }
        }
        const int o0 = w*16 + kgrp*4;
        const float4 bv = *(const float4*)(b3 + o0);
        #pragma unroll
        for (int pf = 0; pf < 4; ++pf) {
            const int p = pf*16 + arow;
            const long pos = pos0 + p;
            const float mv = mask[pos];
            float v0 = leaky(acc[pf][0] + bv.x) * mv;
            float v1 = leaky(acc[pf][1] + bv.y) * mv;
            float v2 = leaky(acc[pf][2] + bv.z) * mv;
            float v3 = leaky(acc[pf][3] + bv.w) * mv;
            *(uint2*)(hout + pos*CC + o0) = make_uint2(pkf(v0, v1), pkf(v2, v3));
        }
    }
}

// ---------------- vectorized reductions: 16B loads, colsum/rowsum/diag ----------------
__global__ __launch_bounds__(256) void reduce_kernel(const short* __restrict__ h,
                                                     float* __restrict__ rowsum,
                                                     float* __restrict__ diag,
                                                     short* __restrict__ rcdh,
                                                     short* __restrict__ rcdl) {
    const int br = blockIdx.x;            // n*128 + r
    const int n = br >> 7, r = br & 127;
    const int t = threadIdx.x;
    const int c8 = (t & 7) * 8;           // 8-channel slice
    const int g = t >> 3;                 // 32 groups
    __shared__ float red[32][64];
    const long rowbase = ((long)(n*NN + r) * NN) * CC;

    // row pass: sum over j
    {
        float s[8];
        #pragma unroll
        for (int e = 0; e < 8; ++e) s[e] = 0.f;
        for (int j = g; j < NN; j += 32) {
            const shortx8 vh = *(const shortx8*)(h + rowbase + (long)j*CC + c8);
            #pragma unroll
            for (int e = 0; e < 8; ++e) s[e] += bf2f(vh[e]);
        }
        #pragma unroll
        for (int e = 0; e < 8; ++e) red[g][c8 + e] = s[e];
    }
    __syncthreads();
    if (t < 64) {
        float rs = 0.f;
        #pragma unroll
        for (int k = 0; k < 32; ++k) rs += red[k][t];
        rowsum[(long)br*CC + t] = rs;
        short hh = f2bf(rs);
        rcdh[(long)br*192 + 64 + t] = hh;
        rcdl[(long)br*192 + 64 + t] = f2bf(rs - bf2f(hh));
    }
    __syncthreads();

    // col pass: sum over i
    {
        const long colbase = ((long)n*NN*NN + r) * CC;
        float s[8];
        #pragma unroll
        for (int e = 0; e < 8; ++e) s[e] = 0.f;
        for (int i = g; i < NN; i += 32) {
            const shortx8 vh = *(const shortx8*)(h + colbase + (long)i*NN*CC + c8);
            #pragma unroll
            for (int e = 0; e < 8; ++e) s[e] += bf2f(vh[e]);
        }
        #pragma unroll
        for (int e = 0; e < 8; ++e) red[g][c8 + e] = s[e];
    }
    __syncthreads();
    if (t < 64) {
        float cs = 0.f;
        #pragma unroll
        for (int k = 0; k < 32; ++k) cs += red[k][t];
        short hh = f2bf(cs);
        rcdh[(long)br*192 + t] = hh;
        rcdl[(long)br*192 + t] = f2bf(cs - bf2f(hh));
        const float dg = bf2f(h[rowbase + (long)r*CC + t]);
        diag[(long)br*CC + t] = dg;
        short hd = f2bf(dg);
        rcdh[(long)br*192 + 128 + t] = hd;
        rcdl[(long)br*192 + 128 + t] = f2bf(dg - bf2f(hd));
    }
}

// ---------------- U/V/D via MFMA, with trace/total biases computed in-block ----------------
__global__ __launch_bounds__(256) void uvd_kernel(
    const short* __restrict__ rcdh, const short* __restrict__ rcdl,
    const short* __restrict__ kh, const short* __restrict__ kl,
    const float* __restrict__ rowsum, const float* __restrict__ diag,
    const float* __restrict__ coefs, int layer,
    float* __restrict__ U, float* __restrict__ V, float* __restrict__ D)
{
    __shared__ float ra[4][64], rb[4][64];
    __shared__ float ub[64], db[64];
    const int t = threadIdx.x, lane = t & 63, w = t >> 6;
    const int arow = lane & 15, kgrp = lane >> 4;
    const int r0 = blockIdx.x * 64;
    const int nb = r0 >> 7;

    // ---- in-block trace/total -> ub/db ----
    {
        const int c = t & 63, g = t >> 6;
        float a = 0.f, b = 0.f;
        for (int i = g; i < NN; i += 4) {
            a += rowsum[((long)nb*NN + i)*CC + c];
            b += diag[((long)nb*NN + i)*CC + c];
        }
        ra[g][c] = a; rb[g][c] = b;
    }
    __syncthreads();
    if (t < 128) {
        const int which = t >> 6, s = t & 63;
        const float* cf = coefs + (long)layer*CC*CC*15;
        float acc = 0.f;
        for (int d = 0; d < CC; ++d) {
            const float tt = ra[0][d] + ra[1][d] + ra[2][d] + ra[3][d];
            const float tr = rb[0][d] + rb[1][d] + rb[2][d] + rb[3][d];
            const float* cds = cf + ((long)d*CC + s)*15;
            if (which == 0) acc += cds[13]*tr + cds[14]*tt;
            else            acc += cds[1]*tr + cds[4]*tt;
        }
        if (which == 0) ub[s] = acc; else db[s] = acc;
    }
    __syncthreads();

    f32x4 acc[3][4];
    #pragma unroll
    for (int o = 0; o < 3; ++o)
        #pragma unroll
        for (int pf = 0; pf < 4; ++pf) acc[o][pf] = (f32x4){0.f,0.f,0.f,0.f};
    #pragma unroll
    for (int kk = 0; kk < 6; ++kk) {
        shortx8 bh[4], bl[4];
        #pragma unroll
        for (int pf = 0; pf < 4; ++pf) {
            const long off = (long)(r0 + pf*16 + arow)*192 + kk*32 + kgrp*8;
            bh[pf] = *(const shortx8*)(rcdh + off);
            bl[pf] = *(const shortx8*)(rcdl + off);
        }
        #pragma unroll
        for (int o = 0; o < 3; ++o) {
            const long aoff = (long)((w*3 + o)*16 + arow)*192 + kk*32 + kgrp*8;
            const shortx8 ah = *(const shortx8*)(kh + aoff);
            const shortx8 al = *(const shortx8*)(kl + aoff);
            #pragma unroll
            for (int pf = 0; pf < 4; ++pf) {
                acc[o][pf] = __builtin_amdgcn_mfma_f32_16x16x32_bf16(ah, bh[pf], acc[o][pf], 0, 0, 0);
                acc[o][pf] = __builtin_amdgcn_mfma_f32_16x16x32_bf16(ah, bl[pf], acc[o][pf], 0, 0, 0);
                acc[o][pf] = __builtin_amdgcn_mfma_f32_16x16x32_bf16(al, bh[pf], acc[o][pf], 0, 0, 0);
            }
        }
    }
    #pragma unroll
    for (int o = 0; o < 3; ++o) {
        const int o16 = (w*3 + o)*16;
        const int o0 = o16 + kgrp*4;
        #pragma unroll
        for (int pf = 0; pf < 4; ++pf) {
            const long rr = r0 + pf*16 + arow;
            float4 a = make_float4(acc[o][pf][0], acc[o][pf][1], acc[o][pf][2], acc[o][pf][3]);
            if (o16 < 64) {
                a.x += ub[o0]; a.y += ub[o0+1]; a.z += ub[o0+2]; a.w += ub[o0+3];
                *(float4*)(U + rr*CC + o0) = a;
            } else if (o16 < 128) {
                *(float4*)(V + rr*CC + (o0 - 64)) = a;
            } else {
                const int q = o0 - 128;
                a.x += db[q]; a.y += db[q+1]; a.z += db[q+2]; a.w += db[q+3];
                *(float4*)(D + rr*CC + q) = a;
            }
        }
    }
}

// ---------------- Eq2to2: symmetric pair-block, bf16 h, split-c only ----------------
__global__ __launch_bounds__(256, 6) void eq_kernel(
    const short* __restrict__ h, const float* __restrict__ mask,
    const short* __restrict__ c9h, const short* __restrict__ c9l,
    const short* __restrict__ c10h, const short* __restrict__ c10l,
    const float* __restrict__ U, const float* __restrict__ V, const float* __restrict__ D,
    const float* __restrict__ bias, const float* __restrict__ idbias,
    float* __restrict__ outf, short* __restrict__ outb)
{
    __shared__ __align__(16) char lds[16384];
    const int t = threadIdx.x, lane = t & 63, w = t >> 6;
    const int arow = lane & 15, kgrp = lane >> 4;
    const int n = blockIdx.y;
    const int pr = blockIdx.x;
    int it = (int)((sqrtf(8.f*pr + 1.f) - 1.f)*0.5f);
    while ((it+1)*(it+2)/2 <= pr) ++it;
    while (it*(it+1)/2 > pr) --it;
    const int jt = pr - it*(it+1)/2;      // jt <= it
    const int i0 = it*8, j0 = jt*8;
    const int s0 = w*16;

    // ---- prefetch c9/c10 fragments ----
    shortx8 A9h[2], A9l[2], A10h[2], A10l[2];
    #pragma unroll
    for (int kk = 0; kk < 2; ++kk) {
        const long co = (long)(s0 + arow)*CC + kk*32 + kgrp*8;
        A9h[kk]  = *(const shortx8*)(c9h  + co);
        A9l[kk]  = *(const shortx8*)(c9l  + co);
        A10h[kk] = *(const shortx8*)(c10h + co);
        A10l[kk] = *(const shortx8*)(c10l + co);
    }

    // ---- stage both tiles, coalesced 32B loads, swizzled 16B ds_writes ----
    {
        const int row = t >> 2, q = t & 3;
        const long posA = ((long)n*NN + i0 + (row >> 3))*NN + (j0 + (row & 7));
        const long posM = ((long)n*NN + j0 + (row & 7))*NN + (i0 + (row >> 3));
        const short* sA = h + posA*CC + q*16;
        const short* sM = h + posM*CC + q*16;
        shortx8 v0 = *(const shortx8*)(sA);
        shortx8 v1 = *(const shortx8*)(sA + 8);
        shortx8 v4 = *(const shortx8*)(sM);
        shortx8 v5 = *(const shortx8*)(sM + 8);
        const int swz = (row & 7) << 4;
        const int d0 = row*128 + ((q*32) ^ swz);
        const int d1 = row*128 + ((q*32 + 16) ^ swz);
        *(shortx8*)(&lds[d0]) = v0;          *(shortx8*)(&lds[d1]) = v1;
        *(shortx8*)(&lds[8192 + d0]) = v4;   *(shortx8*)(&lds[8192 + d1]) = v5;
    }
    __syncthreads();

    f32x4 accA[4], accM[4];
    #pragma unroll
    for (int pf = 0; pf < 4; ++pf) { accA[pf] = (f32x4){0.f,0.f,0.f,0.f}; accM[pf] = (f32x4){0.f,0.f,0.f,0.f}; }

    #pragma unroll
    for (int kk = 0; kk < 2; ++kk) {
        #pragma unroll
        for (int pf = 0; pf < 4; ++pf) {
            const int p = pf*16 + arow;
            const int off = (kk*64 + kgrp*16) ^ ((p & 7) << 4);
            const shortx8 Ah = *(const shortx8*)(&lds[p*128 + off]);
            const shortx8 Mh = *(const shortx8*)(&lds[8192 + p*128 + off]);
            accA[pf] = __builtin_amdgcn_mfma_f32_16x16x32_bf16(A9h[kk],  Ah, accA[pf], 0, 0, 0);
            accA[pf] = __builtin_amdgcn_mfma_f32_16x16x32_bf16(A9l[kk],  Ah, accA[pf], 0, 0, 0);
            accA[pf] = __builtin_amdgcn_mfma_f32_16x16x32_bf16(A10h[kk], Mh, accA[pf], 0, 0, 0);
            accA[pf] = __builtin_amdgcn_mfma_f32_16x16x32_bf16(A10l[kk], Mh, accA[pf], 0, 0, 0);
            accM[pf] = __builtin_amdgcn_mfma_f32_16x16x32_bf16(A9h[kk],  Mh, accM[pf], 0, 0, 0);
            accM[pf] = __builtin_amdgcn_mfma_f32_16x16x32_bf16(A9l[kk],  Mh, accM[pf], 0, 0, 0);
            accM[pf] = __builtin_amdgcn_mfma_f32_16x16x32_bf16(A10h[kk], Ah, accM[pf], 0, 0, 0);
            accM[pf] = __builtin_amdgcn_mfma_f32_16x16x32_bf16(A10l[kk], Ah, accM[pf], 0, 0, 0);
        }
    }

    const int sc = s0 + kgrp*4;
    const float4 bv = *(const float4*)(bias + sc);
    #pragma unroll
    for (int pf = 0; pf < 4; ++pf) {
        const int p = pf*16 + arow;
        // out-A
        {
            const int pi = i0 + (p >> 3), pj = j0 + (p & 7);
            const long pix = ((long)n*NN + pi)*NN + pj;
            const float4 u4 = *(const float4*)(U + ((long)n*NN + pi)*CC + sc);
            const float4 v4 = *(const float4*)(V + ((long)n*NN + pj)*CC + sc);
            float vv[4];
            vv[0] = accA[pf][0] + u4.x + v4.x + bv.x;
            vv[1] = accA[pf][1] + u4.y + v4.y + bv.y;
            vv[2] = accA[pf][2] + u4.z + v4.z + bv.z;
            vv[3] = accA[pf][3] + u4.w + v4.w + bv.w;
            if (it == jt && pi == pj) {
                const float4 d4  = *(const float4*)(D + ((long)n*NN + pi)*CC + sc);
                const float4 db4 = *(const float4*)(idbias + sc);
                vv[0] += d4.x + db4.x; vv[1] += d4.y + db4.y;
                vv[2] += d4.z + db4.z; vv[3] += d4.w + db4.w;
            }
            const float mv = mask[pix];
            #pragma unroll
            for (int r = 0; r < 4; ++r) vv[r] = leaky(vv[r]) * mv;
            if (outf) *(float4*)(outf + pix*CC + sc) = make_float4(vv[0], vv[1], vv[2], vv[3]);
            else      *(uint2*)(outb + pix*CC + sc) = make_uint2(pkf(vv[0], vv[1]), pkf(vv[2], vv[3]));
        }
        // out-M (mirror tile; disjoint when it != jt)
        if (it != jt) {
            const int pi = j0 + (p & 7), pj = i0 + (p >> 3);
            const long pix = ((long)n*NN + pi)*NN + pj;
            const float4 u4 = *(const float4*)(U + ((long)n*NN + pi)*CC + sc);
            const float4 v4 = *(const float4*)(V + ((long)n*NN + pj)*CC + sc);
            float vv[4];
            vv[0] = accM[pf][0] + u4.x + v4.x + bv.x;
            vv[1] = accM[pf][1] + u4.y + v4.y + bv.y;
            vv[2] = accM[pf][2] + u4.z + v4.z + bv.z;
            vv[3] = accM[pf][3] + u4.w + v4.w + bv.w;
            const float mv = mask[pix];
            #pragma unroll
            for (int r = 0; r < 4; ++r) vv[r] = leaky(vv[r]) * mv;
            if (outf) *(float4*)(outf + pix*CC + sc) = make_float4(vv[0], vv[1], vv[2], vv[3]);
            else      *(uint2*)(outb + pix*CC + sc) = make_uint2(pkf(vv[0], vv[1]), pkf(vv[2], vv[3]));
        }
    }
}

extern "C" void kernel_launch(void* const* d_in, const int* in_sizes, int n_in,
                              void* d_out, int out_size, void* d_ws, size_t ws_size,
                              hipStream_t stream) {
    const float* x     = (const float*)d_in[0];
    const float* mask  = (const float*)d_in[1];
    const float* w1    = (const float*)d_in[2];
    const float* b1    = (const float*)d_in[3];
    const float* w2    = (const float*)d_in[4];
    const float* b2    = (const float*)d_in[5];
    const float* w3    = (const float*)d_in[6];
    const float* b3    = (const float*)d_in[7];
    const float* coefs = (const float*)d_in[8];
    const float* bias  = (const float*)d_in[9];
    const float* idb   = (const float*)d_in[10];
    float* out = (float*)d_out;
    float* ws  = (float*)d_ws;

    short* hh     = (short*)(ws + OFF_HHI);
    short* xn     = (short*)(ws + OFF_XN);
    float* rowsum = ws + OFF_RS;
    float* diag   = ws + OFF_DG;
    short* rcdh   = (short*)(ws + OFF_RCDH);
    short* rcdl   = (short*)(ws + OFF_RCDL);
    float* U      = ws + OFF_U;
    float* V      = ws + OFF_V;
    float* D      = ws + OFF_D;
    short* sb     = (short*)(ws + OFF_SB);

    prep_kernel<<<912, 256, 0, stream>>>(w1, w2, w3, coefs, ws);

    for (int l = 0; l < LL; ++l) {
        mlp_kernel<<<NPOS/64, 256, 0, stream>>>(
            (l == 0) ? x : nullptr, (l == 0) ? nullptr : xn, mask,
            b1 + l*HH, b2 + l*HH, b3 + l*CC,
            sb + (long)l*HH*CC, sb + 24576 + (long)l*HH*HH, sb + 73728 + (long)l*CC*HH,
            hh);
        reduce_kernel<<<BB*NN, 256, 0, stream>>>(hh, rowsum, diag, rcdh, rcdl);
        uvd_kernel<<<16, 256, 0, stream>>>(rcdh, rcdl,
            sb + 147456 + (long)l*36864, sb + 258048 + (long)l*36864,
            rowsum, diag, coefs, l, U, V, D);
        eq_kernel<<<dim3(136, BB), 256, 0, stream>>>(
            hh, mask,
            sb + 98304 + (long)l*CC*CC, sb + 110592 + (long)l*CC*CC,
            sb + 122880 + (long)l*CC*CC, sb + 135168 + (long)l*CC*CC,
            U, V, D, bias + l*CC, idb + l*CC,
            (l == LL-1) ? out : nullptr, (l == LL-1) ? nullptr : xn);
    }
}

// Round 9
// 235.964 us; speedup vs baseline: 1.2856x; 1.0126x over previous
//
#include <hip/hip_runtime.h>
#include <hip/hip_bf16.h>

#define BB 8
#define NN 128
#define CC 64
#define LL 3
#define HH 128
#define NEG 0.01f
#define NPOS (BB*NN*NN)   // 131072

typedef __attribute__((ext_vector_type(8))) short shortx8;   // 8 bf16 = 4 VGPRs
typedef __attribute__((ext_vector_type(4))) float f32x4;

// ---- workspace layout (float offsets) ----
#define OFF_HHI   0L          // h bf16: 131072*64 shorts = 4194304 floats
#define OFF_RS2   4194304L    // rowsum2 fp32 [2048][64] (per-mlp-block partials)
#define OFF_XN    8388608L    // inter-layer x (bf16): 4194304 floats
#define OFF_RS    12582912L   // rowsum fp32 [1024][64]
#define OFF_DG    12648448L   // diag fp32 [1024][64]
#define OFF_RCDH  12713984L   // RCD hi [1024][192] shorts = 98304 floats
#define OFF_RCDL  12812288L
#define OFF_U     12911616L   // [1024][64]
#define OFF_V     12977152L
#define OFF_D     13042688L
#define OFF_SB    13108224L   // bf16 const region (shorts)
// sb short offsets: wb1@0 (L*128*64), wb2@24576 (L*128*128), wb3@73728 (L*64*128),
//   c9h@98304, c9l@110592, c10h@122880, c10l@135168 (each L*64*64, [l][s][d]),
//   Kh@147456, Kl@258048 (each L*192*192, [l][out][k])

__device__ __forceinline__ float leaky(float v) { return v >= 0.f ? v : NEG * v; }

__device__ __forceinline__ short f2bf(float f) {
    return (short)__bfloat16_as_ushort(__float2bfloat16(f));
}
__device__ __forceinline__ float bf2f(short s) {
    unsigned u = ((unsigned)(unsigned short)s) << 16;
    return __builtin_bit_cast(float, u);
}
__device__ __forceinline__ unsigned pkf(float a, float b) {  // two f32 -> packed bf16x2
    return (unsigned)(unsigned short)f2bf(a) | ((unsigned)(unsigned short)f2bf(b) << 16);
}
__device__ __forceinline__ shortx8 cvt8(const float* p) {    // 8 f32 -> 8 bf16
    float4 f0 = *(const float4*)p, f1 = *(const float4*)(p + 4);
    shortx8 r;
    r[0]=f2bf(f0.x); r[1]=f2bf(f0.y); r[2]=f2bf(f0.z); r[3]=f2bf(f0.w);
    r[4]=f2bf(f1.x); r[5]=f2bf(f1.y); r[6]=f2bf(f1.z); r[7]=f2bf(f1.w);
    return r;
}

// ---------------- prep: bf16 weights, split c9/c10 [s][d], split K-matrix [out][k] ----------------
__global__ void prep_kernel(const float* __restrict__ w1, const float* __restrict__ w2,
                            const float* __restrict__ w3, const float* __restrict__ coefs,
                            float* __restrict__ ws) {
    long idx = (long)blockIdx.x * 256 + threadIdx.x;
    short* sb = (short*)(ws + OFF_SB);
    if (idx < 24576) {                       // wb1[l][h][c]
        sb[idx] = f2bf(w1[idx]);
    } else if (idx < 73728) {                // wb2[l][h][k]
        sb[idx] = f2bf(w2[idx - 24576]);
    } else if (idx < 98304) {                // wb3[l][c][k]
        sb[idx] = f2bf(w3[idx - 73728]);
    } else if (idx < 110592) {               // c9 hi/lo [l][s][d]
        long r = idx - 98304; int l = (int)(r / 4096); int q = (int)(r % 4096);
        int s = q >> 6, d = q & 63;
        float v = coefs[(((long)l*CC + d)*CC + s)*15 + 9];
        short hi = f2bf(v);
        sb[98304 + r]  = hi;
        sb[110592 + r] = f2bf(v - bf2f(hi));
    } else if (idx < 122880) {               // c10 hi/lo [l][s][d]
        long r = idx - 110592; int l = (int)(r / 4096); int q = (int)(r % 4096);
        int s = q >> 6, d = q & 63;
        float v = coefs[(((long)l*CC + d)*CC + s)*15 + 10];
        short hi = f2bf(v);
        sb[122880 + r] = hi;
        sb[135168 + r] = f2bf(v - bf2f(hi));
    } else if (idx < 233472) {               // Kbig hi/lo [l][out 192][k 192]
        long r = idx - 122880;
        int l = (int)(r / 36864); int q = (int)(r % 36864);
        int o = q / 192, k = q % 192;
        int wo = o >> 6, s = o & 63, wk = k >> 6, d = k & 63;
        const int sel[3][3] = {{5,6,11},{7,8,12},{3,2,0}};
        float v = coefs[(((long)l*CC + d)*CC + s)*15 + sel[wo][wk]];
        short hi = f2bf(v);
        sb[147456 + r] = hi;
        sb[258048 + r] = f2bf(v - bf2f(hi));
    }
}

// ---------------- MFMA fused 3-stage MLP + fused rowsum/diag partials ----------------
// Swapped operands (W = A-frag from global/L2, x = B-frag from LDS).
// LDS: h1@[0,16K), h2@[16K,32K), xt@[16K,24K) (aliases h2 -- xt dead before h2 written).
// Block = half a row (n,i): j in [half*64, half*64+64). Stage-3 epilogue reduces its
// fp32 masked outputs over positions -> rowsum2[blockIdx][64]; writes diag row directly.
__global__ __launch_bounds__(256, 5) void mlp_kernel(
    const float* __restrict__ xf, const short* __restrict__ xb,
    const float* __restrict__ mask,
    const float* __restrict__ b1, const float* __restrict__ b2, const float* __restrict__ b3,
    const short* __restrict__ wb1, const short* __restrict__ wb2, const short* __restrict__ wb3,
    short* __restrict__ hout, float* __restrict__ rowsum2, float* __restrict__ diagOut)
{
    __shared__ __align__(16) char lds[32768];
    const int t = threadIdx.x;
    const int lane = t & 63;
    const int w = t >> 6;
    const int arow = lane & 15;
    const int kgrp = lane >> 4;
    const long pos0 = (long)blockIdx.x * 64;
    const int XT = 16384;

    // ---- stage x -> bf16 LDS tile ----
    {
        const int row = t >> 2, q = t & 3;
        const long off = (pos0 + row)*CC + q*16;
        shortx8 v0, v1;
        if (xb) { v0 = *(const shortx8*)(xb + off); v1 = *(const shortx8*)(xb + off + 8); }
        else    { v0 = cvt8(xf + off);              v1 = cvt8(xf + off + 8); }
        const int swz = (row & 7) << 4;
        *(shortx8*)(&lds[XT + row*128 + ((q*32)      ^ swz)]) = v0;
        *(shortx8*)(&lds[XT + row*128 + ((q*32 + 16) ^ swz)]) = v1;
    }
    __syncthreads();

    // ---- stage 1: 128 outs; wave w -> [w*32, w*32+32) ----
    {
        f32x4 acc[2][4];
        #pragma unroll
        for (int of = 0; of < 2; ++of)
            #pragma unroll
            for (int pf = 0; pf < 4; ++pf) acc[of][pf] = (f32x4){0.f,0.f,0.f,0.f};
        #pragma unroll
        for (int kk = 0; kk < 2; ++kk) {
            shortx8 bx[4];
            #pragma unroll
            for (int pf = 0; pf < 4; ++pf) {
                const int p = pf*16 + arow;
                bx[pf] = *(const shortx8*)(&lds[XT + p*128 + ((kk*64 + kgrp*16) ^ ((p & 7) << 4))]);
            }
            #pragma unroll
            for (int of = 0; of < 2; ++of) {
                const shortx8 a = *(const shortx8*)(wb1 + (long)(w*32 + of*16 + arow)*CC + kk*32 + kgrp*8);
                #pragma unroll
                for (int pf = 0; pf < 4; ++pf)
                    acc[of][pf] = __builtin_amdgcn_mfma_f32_16x16x32_bf16(a, bx[pf], acc[of][pf], 0, 0, 0);
            }
        }
        #pragma unroll
        for (int of = 0; of < 2; ++of) {
            const int o0 = w*32 + of*16 + kgrp*4;
            const float4 bv = *(const float4*)(b1 + o0);
            #pragma unroll
            for (int pf = 0; pf < 4; ++pf) {
                const int p = pf*16 + arow;
                unsigned u0 = pkf(leaky(acc[of][pf][0] + bv.x), leaky(acc[of][pf][1] + bv.y));
                unsigned u1 = pkf(leaky(acc[of][pf][2] + bv.z), leaky(acc[of][pf][3] + bv.w));
                *(uint2*)(&lds[p*256 + ((o0*2) ^ ((p & 15) << 4))]) = make_uint2(u0, u1);
            }
        }
    }
    __syncthreads();

    // ---- stage 2: 128 outs ----
    {
        f32x4 acc[2][4];
        #pragma unroll
        for (int of = 0; of < 2; ++of)
            #pragma unroll
            for (int pf = 0; pf < 4; ++pf) acc[of][pf] = (f32x4){0.f,0.f,0.f,0.f};
        #pragma unroll
        for (int kk = 0; kk < 4; ++kk) {
            shortx8 bx[4];
            #pragma unroll
            for (int pf = 0; pf < 4; ++pf) {
                const int p = pf*16 + arow;
                bx[pf] = *(const shortx8*)(&lds[p*256 + ((kk*64 + kgrp*16) ^ ((p & 15) << 4))]);
            }
            #pragma unroll
            for (int of = 0; of < 2; ++of) {
                const shortx8 a = *(const shortx8*)(wb2 + (long)(w*32 + of*16 + arow)*HH + kk*32 + kgrp*8);
                #pragma unroll
                for (int pf = 0; pf < 4; ++pf)
                    acc[of][pf] = __builtin_amdgcn_mfma_f32_16x16x32_bf16(a, bx[pf], acc[of][pf], 0, 0, 0);
            }
        }
        __syncthreads();   // h1 + xt reads done; h2 region (aliases xt) now writable
        #pragma unroll
        for (int of = 0; of < 2; ++of) {
            const int o0 = w*32 + of*16 + kgrp*4;
            const float4 bv = *(const float4*)(b2 + o0);
            #pragma unroll
            for (int pf = 0; pf < 4; ++pf) {
                const int p = pf*16 + arow;
                unsigned u0 = pkf(leaky(acc[of][pf][0] + bv.x), leaky(acc[of][pf][1] + bv.y));
                unsigned u1 = pkf(leaky(acc[of][pf][2] + bv.z), leaky(acc[of][pf][3] + bv.w));
                *(uint2*)(&lds[16384 + p*256 + ((o0*2) ^ ((p & 15) << 4))]) = make_uint2(u0, u1);
            }
        }
    }
    __syncthreads();

    // ---- stage 3: 64 outs; direct bf16 store + rowsum/diag fusion ----
    {
        f32x4 acc[4];
        #pragma unroll
        for (int pf = 0; pf < 4; ++pf) acc[pf] = (f32x4){0.f,0.f,0.f,0.f};
        #pragma unroll
        for (int kk = 0; kk < 4; ++kk) {
            const shortx8 a = *(const shortx8*)(wb3 + (long)(w*16 + arow)*HH + kk*32 + kgrp*8);
            #pragma unroll
            for (int pf = 0; pf < 4; ++pf) {
                const int p = pf*16 + arow;
                const shortx8 bx = *(const shortx8*)(&lds[16384 + p*256 + ((kk*64 + kgrp*16) ^ ((p & 15) << 4))]);
                acc[pf] = __builtin_amdgcn_mfma_f32_16x16x32_bf16(a, bx, acc[pf], 0, 0, 0);
            }
        }
        const int o0 = w*16 + kgrp*4;
        const float4 bv = *(const float4*)(b3 + o0);
        const int rowIdx = (int)(pos0 >> 7);          // n*128 + i
        const int half64 = (int)(pos0 & 127);         // 0 or 64
        const int pDiag  = (rowIdx & 127) - half64;   // in [0,64) for exactly one block/row
        float rs0 = 0.f, rs1 = 0.f, rs2 = 0.f, rs3 = 0.f;
        #pragma unroll
        for (int pf = 0; pf < 4; ++pf) {
            const int p = pf*16 + arow;
            const long pos = pos0 + p;
            const float mv = mask[pos];
            float v0 = leaky(acc[pf][0] + bv.x) * mv;
            float v1 = leaky(acc[pf][1] + bv.y) * mv;
            float v2 = leaky(acc[pf][2] + bv.z) * mv;
            float v3 = leaky(acc[pf][3] + bv.w) * mv;
            rs0 += v0; rs1 += v1; rs2 += v2; rs3 += v3;
            if (p == pDiag)
                *(float4*)(diagOut + (long)rowIdx*CC + o0) = make_float4(v0, v1, v2, v3);
            *(uint2*)(hout + pos*CC + o0) = make_uint2(pkf(v0, v1), pkf(v2, v3));
        }
        #pragma unroll
        for (int m = 1; m < 16; m <<= 1) {
            rs0 += __shfl_xor(rs0, m);
            rs1 += __shfl_xor(rs1, m);
            rs2 += __shfl_xor(rs2, m);
            rs3 += __shfl_xor(rs3, m);
        }
        if (arow == 0)
            *(float4*)(rowsum2 + (long)blockIdx.x*CC + o0) = make_float4(rs0, rs1, rs2, rs3);
    }
}

// ---------------- colsum + rowsum-combine + rcd pack ----------------
__global__ __launch_bounds__(256) void colsum_kernel(const short* __restrict__ h,
                                                     const float* __restrict__ rowsum2,
                                                     const float* __restrict__ diagIn,
                                                     float* __restrict__ rowsum,
                                                     short* __restrict__ rcdh,
                                                     short* __restrict__ rcdl) {
    const int br = blockIdx.x;            // n*128 + r
    const int n = br >> 7, r = br & 127;
    const int t = threadIdx.x;
    const int c8 = (t & 7) * 8;           // 8-channel slice
    const int g = t >> 3;                 // 32 groups
    __shared__ float red[32][64];

    // col pass: sum over i (h[n][i][j=r][c])
    {
        const long colbase = ((long)n*NN*NN + r) * CC;
        float s[8];
        #pragma unroll
        for (int e = 0; e < 8; ++e) s[e] = 0.f;
        for (int i = g; i < NN; i += 32) {
            const shortx8 vh = *(const shortx8*)(h + colbase + (long)i*NN*CC + c8);
            #pragma unroll
            for (int e = 0; e < 8; ++e) s[e] += bf2f(vh[e]);
        }
        #pragma unroll
        for (int e = 0; e < 8; ++e) red[g][c8 + e] = s[e];
    }
    __syncthreads();
    if (t < 64) {
        float cs = 0.f;
        #pragma unroll
        for (int k = 0; k < 32; ++k) cs += red[k][t];
        short hh = f2bf(cs);
        rcdh[(long)br*192 + t] = hh;
        rcdl[(long)br*192 + t] = f2bf(cs - bf2f(hh));
        // rowsum = two mlp half-row partials
        const float rs = rowsum2[(long)(br*2)*CC + t] + rowsum2[(long)(br*2+1)*CC + t];
        rowsum[(long)br*CC + t] = rs;
        short hr = f2bf(rs);
        rcdh[(long)br*192 + 64 + t] = hr;
        rcdl[(long)br*192 + 64 + t] = f2bf(rs - bf2f(hr));
        // diag (written fp32 by mlp)
        const float dg = diagIn[(long)br*CC + t];
        short hd = f2bf(dg);
        rcdh[(long)br*192 + 128 + t] = hd;
        rcdl[(long)br*192 + 128 + t] = f2bf(dg - bf2f(hd));
    }
}

// ---------------- U/V/D via MFMA, with trace/total biases computed in-block ----------------
__global__ __launch_bounds__(256) void uvd_kernel(
    const short* __restrict__ rcdh, const short* __restrict__ rcdl,
    const short* __restrict__ kh, const short* __restrict__ kl,
    const float* __restrict__ rowsum, const float* __restrict__ diag,
    const float* __restrict__ coefs, int layer,
    float* __restrict__ U, float* __restrict__ V, float* __restrict__ D)
{
    __shared__ float ra[4][64], rb[4][64];
    __shared__ float ub[64], db[64];
    const int t = threadIdx.x, lane = t & 63, w = t >> 6;
    const int arow = lane & 15, kgrp = lane >> 4;
    const int r0 = blockIdx.x * 64;
    const int nb = r0 >> 7;

    // ---- in-block trace/total -> ub/db ----
    {
        const int c = t & 63, g = t >> 6;
        float a = 0.f, b = 0.f;
        for (int i = g; i < NN; i += 4) {
            a += rowsum[((long)nb*NN + i)*CC + c];
            b += diag[((long)nb*NN + i)*CC + c];
        }
        ra[g][c] = a; rb[g][c] = b;
    }
    __syncthreads();
    if (t < 128) {
        const int which = t >> 6, s = t & 63;
        const float* cf = coefs + (long)layer*CC*CC*15;
        float acc = 0.f;
        for (int d = 0; d < CC; ++d) {
            const float tt = ra[0][d] + ra[1][d] + ra[2][d] + ra[3][d];
            const float tr = rb[0][d] + rb[1][d] + rb[2][d] + rb[3][d];
            const float* cds = cf + ((long)d*CC + s)*15;
            if (which == 0) acc += cds[13]*tr + cds[14]*tt;
            else            acc += cds[1]*tr + cds[4]*tt;
        }
        if (which == 0) ub[s] = acc; else db[s] = acc;
    }
    __syncthreads();

    f32x4 acc[3][4];
    #pragma unroll
    for (int o = 0; o < 3; ++o)
        #pragma unroll
        for (int pf = 0; pf < 4; ++pf) acc[o][pf] = (f32x4){0.f,0.f,0.f,0.f};
    #pragma unroll
    for (int kk = 0; kk < 6; ++kk) {
        shortx8 bh[4], bl[4];
        #pragma unroll
        for (int pf = 0; pf < 4; ++pf) {
            const long off = (long)(r0 + pf*16 + arow)*192 + kk*32 + kgrp*8;
            bh[pf] = *(const shortx8*)(rcdh + off);
            bl[pf] = *(const shortx8*)(rcdl + off);
        }
        #pragma unroll
        for (int o = 0; o < 3; ++o) {
            const long aoff = (long)((w*3 + o)*16 + arow)*192 + kk*32 + kgrp*8;
            const shortx8 ah = *(const shortx8*)(kh + aoff);
            const shortx8 al = *(const shortx8*)(kl + aoff);
            #pragma unroll
            for (int pf = 0; pf < 4; ++pf) {
                acc[o][pf] = __builtin_amdgcn_mfma_f32_16x16x32_bf16(ah, bh[pf], acc[o][pf], 0, 0, 0);
                acc[o][pf] = __builtin_amdgcn_mfma_f32_16x16x32_bf16(ah, bl[pf], acc[o][pf], 0, 0, 0);
                acc[o][pf] = __builtin_amdgcn_mfma_f32_16x16x32_bf16(al, bh[pf], acc[o][pf], 0, 0, 0);
            }
        }
    }
    #pragma unroll
    for (int o = 0; o < 3; ++o) {
        const int o16 = (w*3 + o)*16;
        const int o0 = o16 + kgrp*4;
        #pragma unroll
        for (int pf = 0; pf < 4; ++pf) {
            const long rr = r0 + pf*16 + arow;
            float4 a = make_float4(acc[o][pf][0], acc[o][pf][1], acc[o][pf][2], acc[o][pf][3]);
            if (o16 < 64) {
                a.x += ub[o0]; a.y += ub[o0+1]; a.z += ub[o0+2]; a.w += ub[o0+3];
                *(float4*)(U + rr*CC + o0) = a;
            } else if (o16 < 128) {
                *(float4*)(V + rr*CC + (o0 - 64)) = a;
            } else {
                const int q = o0 - 128;
                a.x += db[q]; a.y += db[q+1]; a.z += db[q+2]; a.w += db[q+3];
                *(float4*)(D + rr*CC + q) = a;
            }
        }
    }
}

// ---------------- Eq2to2: symmetric pair-block, bf16 h, split-c only ----------------
__global__ __launch_bounds__(256, 6) void eq_kernel(
    const short* __restrict__ h, const float* __restrict__ mask,
    const short* __restrict__ c9h, const short* __restrict__ c9l,
    const short* __restrict__ c10h, const short* __restrict__ c10l,
    const float* __restrict__ U, const float* __restrict__ V, const float* __restrict__ D,
    const float* __restrict__ bias, const float* __restrict__ idbias,
    float* __restrict__ outf, short* __restrict__ outb)
{
    __shared__ __align__(16) char lds[16384];
    const int t = threadIdx.x, lane = t & 63, w = t >> 6;
    const int arow = lane & 15, kgrp = lane >> 4;
    const int n = blockIdx.y;
    const int pr = blockIdx.x;
    int it = (int)((sqrtf(8.f*pr + 1.f) - 1.f)*0.5f);
    while ((it+1)*(it+2)/2 <= pr) ++it;
    while (it*(it+1)/2 > pr) --it;
    const int jt = pr - it*(it+1)/2;      // jt <= it
    const int i0 = it*8, j0 = jt*8;
    const int s0 = w*16;

    // ---- prefetch c9/c10 fragments ----
    shortx8 A9h[2], A9l[2], A10h[2], A10l[2];
    #pragma unroll
    for (int kk = 0; kk < 2; ++kk) {
        const long co = (long)(s0 + arow)*CC + kk*32 + kgrp*8;
        A9h[kk]  = *(const shortx8*)(c9h  + co);
        A9l[kk]  = *(const shortx8*)(c9l  + co);
        A10h[kk] = *(const shortx8*)(c10h + co);
        A10l[kk] = *(const shortx8*)(c10l + co);
    }

    // ---- stage both tiles, coalesced 32B loads, swizzled 16B ds_writes ----
    {
        const int row = t >> 2, q = t & 3;
        const long posA = ((long)n*NN + i0 + (row >> 3))*NN + (j0 + (row & 7));
        const long posM = ((long)n*NN + j0 + (row & 7))*NN + (i0 + (row >> 3));
        const short* sA = h + posA*CC + q*16;
        const short* sM = h + posM*CC + q*16;
        shortx8 v0 = *(const shortx8*)(sA);
        shortx8 v1 = *(const shortx8*)(sA + 8);
        shortx8 v4 = *(const shortx8*)(sM);
        shortx8 v5 = *(const shortx8*)(sM + 8);
        const int swz = (row & 7) << 4;
        const int d0 = row*128 + ((q*32) ^ swz);
        const int d1 = row*128 + ((q*32 + 16) ^ swz);
        *(shortx8*)(&lds[d0]) = v0;          *(shortx8*)(&lds[d1]) = v1;
        *(shortx8*)(&lds[8192 + d0]) = v4;   *(shortx8*)(&lds[8192 + d1]) = v5;
    }
    __syncthreads();

    f32x4 accA[4], accM[4];
    #pragma unroll
    for (int pf = 0; pf < 4; ++pf) { accA[pf] = (f32x4){0.f,0.f,0.f,0.f}; accM[pf] = (f32x4){0.f,0.f,0.f,0.f}; }

    #pragma unroll
    for (int kk = 0; kk < 2; ++kk) {
        #pragma unroll
        for (int pf = 0; pf < 4; ++pf) {
            const int p = pf*16 + arow;
            const int off = (kk*64 + kgrp*16) ^ ((p & 7) << 4);
            const shortx8 Ah = *(const shortx8*)(&lds[p*128 + off]);
            const shortx8 Mh = *(const shortx8*)(&lds[8192 + p*128 + off]);
            accA[pf] = __builtin_amdgcn_mfma_f32_16x16x32_bf16(A9h[kk],  Ah, accA[pf], 0, 0, 0);
            accA[pf] = __builtin_amdgcn_mfma_f32_16x16x32_bf16(A9l[kk],  Ah, accA[pf], 0, 0, 0);
            accA[pf] = __builtin_amdgcn_mfma_f32_16x16x32_bf16(A10h[kk], Mh, accA[pf], 0, 0, 0);
            accA[pf] = __builtin_amdgcn_mfma_f32_16x16x32_bf16(A10l[kk], Mh, accA[pf], 0, 0, 0);
            accM[pf] = __builtin_amdgcn_mfma_f32_16x16x32_bf16(A9h[kk],  Mh, accM[pf], 0, 0, 0);
            accM[pf] = __builtin_amdgcn_mfma_f32_16x16x32_bf16(A9l[kk],  Mh, accM[pf], 0, 0, 0);
            accM[pf] = __builtin_amdgcn_mfma_f32_16x16x32_bf16(A10h[kk], Ah, accM[pf], 0, 0, 0);
            accM[pf] = __builtin_amdgcn_mfma_f32_16x16x32_bf16(A10l[kk], Ah, accM[pf], 0, 0, 0);
        }
    }

    const int sc = s0 + kgrp*4;
    const float4 bv = *(const float4*)(bias + sc);
    #pragma unroll
    for (int pf = 0; pf < 4; ++pf) {
        const int p = pf*16 + arow;
        // out-A
        {
            const int pi = i0 + (p >> 3), pj = j0 + (p & 7);
            const long pix = ((long)n*NN + pi)*NN + pj;
            const float4 u4 = *(const float4*)(U + ((long)n*NN + pi)*CC + sc);
            const float4 v4 = *(const float4*)(V + ((long)n*NN + pj)*CC + sc);
            float vv[4];
            vv[0] = accA[pf][0] + u4.x + v4.x + bv.x;
            vv[1] = accA[pf][1] + u4.y + v4.y + bv.y;
            vv[2] = accA[pf][2] + u4.z + v4.z + bv.z;
            vv[3] = accA[pf][3] + u4.w + v4.w + bv.w;
            if (it == jt && pi == pj) {
                const float4 d4  = *(const float4*)(D + ((long)n*NN + pi)*CC + sc);
                const float4 db4 = *(const float4*)(idbias + sc);
                vv[0] += d4.x + db4.x; vv[1] += d4.y + db4.y;
                vv[2] += d4.z + db4.z; vv[3] += d4.w + db4.w;
            }
            const float mv = mask[pix];
            #pragma unroll
            for (int r = 0; r < 4; ++r) vv[r] = leaky(vv[r]) * mv;
            if (outf) *(float4*)(outf + pix*CC + sc) = make_float4(vv[0], vv[1], vv[2], vv[3]);
            else      *(uint2*)(outb + pix*CC + sc) = make_uint2(pkf(vv[0], vv[1]), pkf(vv[2], vv[3]));
        }
        // out-M (mirror tile; disjoint when it != jt)
        if (it != jt) {
            const int pi = j0 + (p & 7), pj = i0 + (p >> 3);
            const long pix = ((long)n*NN + pi)*NN + pj;
            const float4 u4 = *(const float4*)(U + ((long)n*NN + pi)*CC + sc);
            const float4 v4 = *(const float4*)(V + ((long)n*NN + pj)*CC + sc);
            float vv[4];
            vv[0] = accM[pf][0] + u4.x + v4.x + bv.x;
            vv[1] = accM[pf][1] + u4.y + v4.y + bv.y;
            vv[2] = accM[pf][2] + u4.z + v4.z + bv.z;
            vv[3] = accM[pf][3] + u4.w + v4.w + bv.w;
            const float mv = mask[pix];
            #pragma unroll
            for (int r = 0; r < 4; ++r) vv[r] = leaky(vv[r]) * mv;
            if (outf) *(float4*)(outf + pix*CC + sc) = make_float4(vv[0], vv[1], vv[2], vv[3]);
            else      *(uint2*)(outb + pix*CC + sc) = make_uint2(pkf(vv[0], vv[1]), pkf(vv[2], vv[3]));
        }
    }
}

extern "C" void kernel_launch(void* const* d_in, const int* in_sizes, int n_in,
                              void* d_out, int out_size, void* d_ws, size_t ws_size,
                              hipStream_t stream) {
    const float* x     = (const float*)d_in[0];
    const float* mask  = (const float*)d_in[1];
    const float* w1    = (const float*)d_in[2];
    const float* b1    = (const float*)d_in[3];
    const float* w2    = (const float*)d_in[4];
    const float* b2    = (const float*)d_in[5];
    const float* w3    = (const float*)d_in[6];
    const float* b3    = (const float*)d_in[7];
    const float* coefs = (const float*)d_in[8];
    const float* bias  = (const float*)d_in[9];
    const float* idb   = (const float*)d_in[10];
    float* out = (float*)d_out;
    float* ws  = (float*)d_ws;

    short* hh      = (short*)(ws + OFF_HHI);
    float* rowsum2 = ws + OFF_RS2;
    short* xn      = (short*)(ws + OFF_XN);
    float* rowsum  = ws + OFF_RS;
    float* diag    = ws + OFF_DG;
    short* rcdh    = (short*)(ws + OFF_RCDH);
    short* rcdl    = (short*)(ws + OFF_RCDL);
    float* U       = ws + OFF_U;
    float* V       = ws + OFF_V;
    float* D       = ws + OFF_D;
    short* sb      = (short*)(ws + OFF_SB);

    prep_kernel<<<912, 256, 0, stream>>>(w1, w2, w3, coefs, ws);

    for (int l = 0; l < LL; ++l) {
        mlp_kernel<<<NPOS/64, 256, 0, stream>>>(
            (l == 0) ? x : nullptr, (l == 0) ? nullptr : xn, mask,
            b1 + l*HH, b2 + l*HH, b3 + l*CC,
            sb + (long)l*HH*CC, sb + 24576 + (long)l*HH*HH, sb + 73728 + (long)l*CC*HH,
            hh, rowsum2, diag);
        colsum_kernel<<<BB*NN, 256, 0, stream>>>(hh, rowsum2, diag, rowsum, rcdh, rcdl);
        uvd_kernel<<<16, 256, 0, stream>>>(rcdh, rcdl,
            sb + 147456 + (long)l*36864, sb + 258048 + (long)l*36864,
            rowsum, diag, coefs, l, U, V, D);
        eq_kernel<<<dim3(136, BB), 256, 0, stream>>>(
            hh, mask,
            sb + 98304 + (long)l*CC*CC, sb + 110592 + (long)l*CC*CC,
            sb + 122880 + (long)l*CC*CC, sb + 135168 + (long)l*CC*CC,
            U, V, D, bias + l*CC, idb + l*CC,
            (l == LL-1) ? out : nullptr, (l == LL-1) ? nullptr : xn);
    }
}